// Round 12
// baseline (812.576 us; speedup 1.0000x reference)
//
#include <hip/hip_runtime.h>
#include <hip/hip_bf16.h>

// GCLSTM: B=512, T=32, H=300, K=10. f32 in/out.
// R12 = R11 + guarded cells-dedup split:
//   if ws >= 198.3MB: kern_cells writes con_g (bf16, once per (t,b,k,h));
//     kern_main_split loads con(t), con(t-1) from con_g (P1 compute deleted).
//   else: kern_main_mono == R11 kern_main verbatim (752us known-good).
// Dispatched kernel name in rocprof = ws_size probe.

#define TB 2
#define NR 32             // cct rows (MFMA N)
#define NTHR 640          // 10 waves
#define NW 10
#define KP 616
#define TBF 4             // kern_final b-tile

// ws layout (u32 slots) — identical to R11
#define OFF_SM    0         // softmax [32][10][512] f32          163840
#define OFF_WBF2  163840    // wp A-frags [mt19][ks19][lane64][4]  92416
#define OFF_F1S   256256    // F1 B-frags [nt13][ks19][lane64][4]  63232
#define OFF_WIHP2 319488    // cells [k10][h300][36] f32 (33-35=bias) 108000
#define OFF_BTP   427488    // g*300+h f32                           900
#define OFF_WTP   428388    // (e*3+g)*300+h f32                    3600
#define OFF_WA    431988    // softmax(DisM) f32                      10
#define OFF_SWA   431998    // sum(wA) f32                             1
#define BASE_U32  432000
#define CON1_BYTE ((size_t)BASE_U32 * 4)                  // 1,728,000
#define WS_MIN_BYTES (CON1_BYTE + (size_t)98304000)       // 100,032,000
#define CONG_BYTE  WS_MIN_BYTES                           // con_g right after con1u
#define WS_SPLIT_BYTES (CONG_BYTE + (size_t)98304000)     // 198,336,000

typedef __attribute__((ext_vector_type(8))) short s16x8;
typedef __attribute__((ext_vector_type(4))) float f32x4;
typedef unsigned short u16;

__device__ __forceinline__ float sigf(float x){ return 1.0f/(1.0f+__expf(-x)); }
__device__ __forceinline__ float tanhf_(float x){ return 1.0f - 2.0f/(__expf(2.0f*x)+1.0f); }
__device__ __forceinline__ float bfu(u16 u){ return __uint_as_float(((unsigned)u)<<16); }
__device__ __forceinline__ u16 f2us(float f){ return (u16)(__float_as_uint(f)>>16); }
__device__ __forceinline__ u16 f2usr(float f){   // RNE bf16
  __hip_bfloat16 h = __float2bfloat16(f);
  return *(u16*)&h;
}

// ============ split path: cells once per (t,b,k,h) -> con_g bf16 ============
__global__ __launch_bounds__(NTHR,2) void kern_cells(
    const float* __restrict__ li, const float* wsf, u16* __restrict__ cong)
{
  __shared__ float xsT[10][TB][11];   // [k][b][i]
  const int tid=threadIdx.x, bt=blockIdx.x, t=blockIdx.y, b0=bt*TB;
  for (int p=tid; p<TB*110; p+=NTHR){
    int b=p/110, r=p%110, i=r/10, k=r%10;
    xsT[k][b][i] = li[(((b0+b)*32+t)*28+i)*10+k];
  }
  __syncthreads();
  const int k = tid>>6, h0 = tid&63;
  float xv[TB][11];
  #pragma unroll
  for (int b=0;b<TB;b++)
    #pragma unroll
    for (int i=0;i<11;i++) xv[b][i] = xsT[k][b][i];
  for (int h=h0; h<300; h+=64){
    const float4* Wp = (const float4*)(wsf + OFF_WIHP2 + (size_t)(k*300+h)*36);
    float f[36];
    #pragma unroll
    for (int q=0;q<9;q++){
      float4 v = Wp[q];
      f[4*q+0]=v.x; f[4*q+1]=v.y; f[4*q+2]=v.z; f[4*q+3]=v.w;
    }
    #pragma unroll
    for (int b=0;b<TB;b++){
      float ai=f[33], ag=f[34], ao=f[35];
      #pragma unroll
      for (int i=0;i<11;i++){
        float xvv = xv[b][i];
        ai += f[3*i+0]*xvv; ag += f[3*i+1]*xvv; ao += f[3*i+2]*xvv;
      }
      float hv = sigf(ao) * tanhf_( sigf(ai) * tanhf_(ag) );
      cong[ ((size_t)(t*256+bt)*20 + b*10+k)*300 + h ] = f2usr(hv);
    }
  }
}

// ============ kern_main body shared by both paths via template ============
// SPLIT=1: P1 loads con from con_g. SPLIT=0: P1 computes cells inline (R11).
template<int SPLIT>
__device__ __forceinline__ void kern_main_body(
    const float* __restrict__ li, const float* __restrict__ exs,
    const float* __restrict__ AngleM, const float* __restrict__ bp,
    const float* __restrict__ F2, const float* __restrict__ b2,
    const float* wsf, unsigned* __restrict__ con1u, float* smg,
    const u16* __restrict__ cong)
{
  __shared__ __align__(16) u16 cct[NR][KP];   // 39,424 B
  __shared__ float xs[2][TB][11][10];         //  1,760 (unused loads in SPLIT=1)
  __shared__ float xse[TB][2][10];
  __shared__ float exss[TB][4];
  __shared__ float wdP[NW][NR];
  __shared__ float wdL[NR];
  const int tid = threadIdx.x;
  const int t = blockIdx.y, bt = blockIdx.x, b0 = bt*TB;
  const int w = tid>>6, lane = tid&63, lo = lane&15, qd = lane>>4;

  // ---- P0 ----
  if (!SPLIT){
    for (int p=tid; p<2*TB*110; p+=NTHR){
      int half=p/(110*TB), r=p%(110*TB), b=r/110, q=r%110, i=q/10, k=q%10;
      int tp = half ? (t>0? t-1 : 0) : t;
      xs[half][b][i][k] = li[(((b0+b)*32+tp)*28+i)*10+k];
    }
  }
  for (int p=tid;p<TB*20;p+=NTHR){
    int b=p/20, r=p%20, rr=r/10, k=r%10;
    xse[b][rr][k] = li[(((b0+b)*32+t)*28 + (rr?10:8))*10 + k];
  }
  for (int p=tid;p<TB*4;p+=NTHR){
    int b=p/4, e=p%4;
    exss[b][e] = exs[((b0+b)*32+t)*4+e];
  }
  for (int p=tid; p<20*4; p+=NTHR){            // rows 0..19, cols 600-607
    int n=p/4, c=p%4;
    ((unsigned*)&cct[n][600])[c] = 0u;
  }
  for (int p=tid; p<12*(KP/2); p+=NTHR){       // rows 20..31 full
    int n=20+p/(KP/2), c=p%(KP/2);
    ((unsigned*)&cct[n][0])[c] = 0u;
  }
  __syncthreads();

  // ---- P1: con(t) -> cols 0-299, con(t-1) -> cols 300-599 ----
  const int nh = (t==0)?1:2;
  if (SPLIT){
    for (int p=tid; p<nh*3000; p+=NTHR){
      int half=p/3000, r=p%3000, n=r/150, op=r%150;
      int tp = half? t-1 : t;
      unsigned v = ((const unsigned*)cong)[ ((size_t)(tp*256+bt)*20+n)*150 + op ];
      *(unsigned*)&cct[n][300*half + 2*op] = v;
    }
  } else {
    for (int pt=tid; pt<3000; pt+=NTHR){
      int k=pt/300, h=pt%300;
      const float4* Wp = (const float4*)(wsf + OFF_WIHP2 + (size_t)(k*300+h)*36);
      float f[36];
      #pragma unroll
      for (int q=0;q<9;q++){
        float4 v = Wp[q];
        f[4*q+0]=v.x; f[4*q+1]=v.y; f[4*q+2]=v.z; f[4*q+3]=v.w;
      }
      for (int half=0; half<nh; half++){
        #pragma unroll
        for (int b=0;b<TB;b++){
          float ai=f[33], ag=f[34], ao=f[35];
          #pragma unroll
          for (int i=0;i<11;i++){
            float xv = xs[half][b][i][k];
            ai += f[3*i+0]*xv; ag += f[3*i+1]*xv; ao += f[3*i+2]*xv;
          }
          float hv = sigf(ao) * tanhf_( sigf(ai) * tanhf_(ag) );
          cct[b*10+k][h+300*half] = f2usr(hv);
        }
      }
    }
  }
  __syncthreads();

  // ---- P2: wp-MFMA  D[o 304][n 32]; 2 Mtiles/wave, 2 Ntiles ----
  f32x4 acc[2][2];
  #pragma unroll
  for (int i=0;i<2;i++)
    #pragma unroll
    for (int nt=0;nt<2;nt++) acc[i][nt] = (f32x4){0.f,0.f,0.f,0.f};
  if (t>0){
    const u16* wbfA = (const u16*)((const unsigned*)wsf + OFF_WBF2);
    for (int ks=0; ks<19; ks++){
      const int kb = ks*32 + qd*8;
      s16x8 Bv[2];
      #pragma unroll
      for (int nt=0;nt<2;nt++)
        Bv[nt] = *(const s16x8*)&cct[nt*16+lo][kb];
      #pragma unroll
      for (int i=0;i<2;i++){
        int mt = w*2+i;
        if (mt<19){
          s16x8 Av = *(const s16x8*)(wbfA + ((size_t)(mt*19+ks)*64 + lane)*8);
          #pragma unroll
          for (int nt=0;nt<2;nt++)
            acc[i][nt] = __builtin_amdgcn_mfma_f32_16x16x32_bf16(Av, Bv[nt], acc[i][nt], 0,0,0);
        }
      }
    }
  }
  __syncthreads();

  // ---- P2b (t>0): epilogue transpose: cct[n][o] = relu(D+bp) bf16, o<300 ----
  if (t>0){
    #pragma unroll
    for (int i=0;i<2;i++){
      int mt = w*2+i;
      if (mt<19 && (mt<18 || qd<3)){
        int ob = mt*16 + qd*4;
        float p0=bp[ob], p1=bp[ob+1], p2=bp[ob+2], p3=bp[ob+3];
        #pragma unroll
        for (int nt=0;nt<2;nt++){
          int n = nt*16+lo;
          float v0=acc[i][nt][0]+p0, v1=acc[i][nt][1]+p1,
                v2=acc[i][nt][2]+p2, v3=acc[i][nt][3]+p3;
          unsigned w0 = ((unsigned)f2us(v1>0.f?v1:0.f)<<16) | f2us(v0>0.f?v0:0.f);
          unsigned w1 = ((unsigned)f2us(v3>0.f?v3:0.f)<<16) | f2us(v2>0.f?v2:0.f);
          *(unsigned*)&cct[n][ob]   = w0;
          *(unsigned*)&cct[n][ob+2] = w1;
        }
      }
    }
  }
  // ---- P3: htarget -> hcat cols [300,600); col 600 = 1.0 ----
  for (int p=tid; p<TB*300; p+=NTHR){
    int b=p/300, o=p%300;
    float ai=0.f, ag=0.f, ao=0.f;
    #pragma unroll
    for (int e=0;e<4;e++){
      float xv = exss[b][e];
      ai += wsf[OFF_WTP+(e*3+0)*300+o]*xv;
      ag += wsf[OFF_WTP+(e*3+1)*300+o]*xv;
      ao += wsf[OFF_WTP+(e*3+2)*300+o]*xv;
    }
    ai += wsf[OFF_BTP+o]; ag += wsf[OFF_BTP+300+o]; ao += wsf[OFF_BTP+600+o];
    u16 u = f2usr( sigf(ao)*tanhf_(sigf(ai)*tanhf_(ag)) );
    #pragma unroll
    for (int k=0;k<10;k++) cct[b*10+k][300+o] = u;
  }
  for (int p=tid; p<20*4; p+=NTHR){
    int n=p/4, c=p%4;
    ((unsigned*)&cct[n][600])[c] = (c==0)? 0x00003f80u : 0u;
  }
  __syncthreads();

  // ---- P5: store con1 tile [n 20][o 300] coalesced ----
  for (int p=tid; p<TB*1500; p+=NTHR){
    int n=p/150, op=p%150;
    con1u[ ((size_t)(t*256+bt)*20 + n)*150 + op ] = *(const unsigned*)&cct[n][2*op];
  }

  // ---- P4: F1-MFMA  fc1[n 32][j 208]; 2 Mtiles, nt in {w, w+10} ----
  f32x4 acc2[2][2];
  #pragma unroll
  for (int mt=0;mt<2;mt++)
    #pragma unroll
    for (int j=0;j<2;j++) acc2[mt][j] = (f32x4){0.f,0.f,0.f,0.f};
  {
    const u16* f1s = (const u16*)((const unsigned*)wsf + OFF_F1S);
    for (int ks=0; ks<19; ks++){
      const int kb = ks*32 + qd*8;
      s16x8 Am[2];
      #pragma unroll
      for (int mt=0;mt<2;mt++)
        Am[mt] = *(const s16x8*)&cct[mt*16+lo][kb];
      #pragma unroll
      for (int j=0;j<2;j++){
        int nt = w + j*NW;
        if (nt<13){
          s16x8 Bf = *(const s16x8*)(f1s + ((size_t)(nt*19+ks)*64 + lane)*8);
          #pragma unroll
          for (int mt=0;mt<2;mt++)
            acc2[mt][j] = __builtin_amdgcn_mfma_f32_16x16x32_bf16(Am[mt], Bf, acc2[mt][j], 0,0,0);
        }
      }
    }
  }
  {
    float f2c[2];
    #pragma unroll
    for (int j=0;j<2;j++){
      int nt = w + j*NW;
      int jj = nt*16+lo;
      f2c[j] = (nt<13 && jj<200)? F2[jj] : 0.f;
    }
    #pragma unroll
    for (int mt=0;mt<2;mt++)
      #pragma unroll
      for (int r=0;r<4;r++){
        float s = 0.f;
        #pragma unroll
        for (int j=0;j<2;j++){
          float v = acc2[mt][j][r];
          s += (v>0.f? v:0.f) * f2c[j];
        }
        s += __shfl_xor(s,1,64); s += __shfl_xor(s,2,64);
        s += __shfl_xor(s,4,64); s += __shfl_xor(s,8,64);
        if (lo==0) wdP[w][mt*16+qd*4+r] = s;
      }
  }
  __syncthreads();
  if (tid<TB*10){
    int n=tid, b=n/10, k=n%10;
    float v = 0.f;
    #pragma unroll
    for (int ww=0;ww<NW;ww++) v += wdP[ww][n];
    float ang = fabsf(xse[b][1][k]-AngleM[k]) * (1.0f/360.0f);
    v += xse[b][0][k]*F2[200] + ang*F2[201] + b2[0];
    wdL[n] = v>0.f? v : 0.f;
  }
  __syncthreads();
  if (tid<TB){
    int b=tid;
    float m = wdL[b*10];
    #pragma unroll
    for (int k=1;k<10;k++) m = fmaxf(m, wdL[b*10+k]);
    float e[10]; float s=0.f;
    #pragma unroll
    for (int k=0;k<10;k++){ e[k]=__expf(wdL[b*10+k]-m); s+=e[k]; }
    float inv = 1.0f/s;
    #pragma unroll
    for (int k=0;k<10;k++) smg[t*5120 + k*512 + b0+b] = e[k]*inv;
  }
}

__global__ __launch_bounds__(NTHR,2) void kern_main_mono(
    const float* __restrict__ li, const float* __restrict__ exs,
    const float* __restrict__ AngleM, const float* __restrict__ bp,
    const float* __restrict__ F2, const float* __restrict__ b2,
    const float* wsf, unsigned* __restrict__ con1u, float* smg)
{
  kern_main_body<0>(li,exs,AngleM,bp,F2,b2,wsf,con1u,smg,(const u16*)nullptr);
}

__global__ __launch_bounds__(NTHR,2) void kern_main_split(
    const float* __restrict__ li, const float* __restrict__ exs,
    const float* __restrict__ AngleM, const float* __restrict__ bp,
    const float* __restrict__ F2, const float* __restrict__ b2,
    const float* wsf, unsigned* __restrict__ con1u, float* smg,
    const u16* __restrict__ cong)
{
  kern_main_body<1>(li,exs,AngleM,bp,F2,b2,wsf,con1u,smg,cong);
}

// ====== final: gather scramble, fuse, preds (+ labels copy fused); TBF=4 ======
__global__ __launch_bounds__(NTHR,3) void kern_final(
    const float* __restrict__ li, const float* __restrict__ labels,
    const float* __restrict__ ff, const float* __restrict__ bff,
    const float* __restrict__ fuse1, const float* __restrict__ biasf,
    const float* __restrict__ Wout, const float* __restrict__ biasout,
    const float* __restrict__ a, const float* wsf,
    const unsigned* __restrict__ con1u, float* __restrict__ outp)
{
  __shared__ unsigned conTu[40][152];
  __shared__ float xs17[TBF][17][10];
  __shared__ float cats[TBF][300];
  __shared__ float wa3s[TBF][10];
  __shared__ float dss[TBF][17];
  __shared__ float wAs[10];
  __shared__ float fup1[8][64], fup2[8][64];
  const int tid=threadIdx.x, t=blockIdx.y, bt=blockIdx.x, b0=bt*TBF;
  if (tid>=NTHR-TBF && tid<NTHR){
    int b = tid-(NTHR-TBF);
    outp[16384 + t*512 + b0+b] = labels[(b0+b)*32+t];
  }
  for (int p=tid;p<TBF*170;p+=NTHR){
    int b=p/170, r=p%170, f=r/10, k=r%10;
    xs17[b][f][k] = li[(((b0+b)*32+t)*28 + 11+f)*10 + k];
  }
  if (tid<10) wAs[tid] = wsf[OFF_WA+tid];
  for (int p=tid;p<6000;p+=NTHR){
    int n4=p/150, op=p%150;
    int b=n4/10, k=n4%10, bg=b0+b;
    conTu[n4][op] = con1u[ ((size_t)(t*256+(bg>>1))*20 + (bg&1)*10 + k)*150 + op ];
  }
  __syncthreads();
  for (int p=tid;p<TBF*10;p+=NTHR){
    int b=p/10, k=p%10;
    int g = (b0+b)*10+k;
    wa3s[b][k] = wsf[OFF_SM + t*5120 + (g>>9)*512 + (g&511)];
  }
  for (int p=tid;p<TBF*17;p+=NTHR){
    int b=p/17, f=p%17; float s=0.f;
    #pragma unroll
    for (int k=0;k<10;k++) s += xs17[b][f][k]*wAs[k];
    dss[b][f]=s;
  }
  __syncthreads();
  const u16* conT = (const u16*)conTu;
  for (int p=tid;p<TBF*300;p+=NTHR){
    int b=p/300, h=p%300;
    float s=0.f;
    #pragma unroll
    for (int k=0;k<10;k++)
      s += bfu(conT[(b*10+k)*304 + h]) * wa3s[b][k];
    cats[b][h]=s;
  }
  __syncthreads();
  const int w = tid>>6, lane = tid&63;
  const int o1 = lane;
  const bool o2v = lane<36;
  const int o2 = o2v ? (64+lane) : 99;
  if (w<8){
    int b=w>>1, half=w&1;
    float fu1 = half? 0.f : biasf[o1];
    float fu2 = half? 0.f : biasf[o2];
    const int hb = half*150;
    for (int h=hb; h<hb+150; h++){
      float cv = cats[b][h];
      fu1 += cv*fuse1[h*100+o1];
      fu2 += cv*fuse1[h*100+o2];
    }
    fup1[w][lane]=fu1; fup2[w][lane]=fu2;
  }
  __syncthreads();
  if (w<TBF){
    const int b=w, bg=b0+b;
    const float aa = a[0], swa = wsf[OFF_SWA];
    float fu1 = fup1[2*b][lane] + fup1[2*b+1][lane];
    float fu2 = fup2[2*b][lane] + fup2[2*b+1][lane];
    float fd1 = bff[o1]*swa, fd2 = bff[o2]*swa;
    #pragma unroll
    for (int f=0;f<17;f++){
      float dv = dss[b][f];
      fd1 += ff[o1*17+f]*dv;
      fd2 += ff[o2*17+f]*dv;
    }
    float v = (aa*fu1+(1.f-aa)*fd1)*Wout[o1];
    if (o2v) v += (aa*fu2+(1.f-aa)*fd2)*Wout[o2];
    #pragma unroll
    for (int off=32;off>=1;off>>=1) v += __shfl_xor(v,off,64);
    if (lane==0) outp[t*512+bg] = v + biasout[0];
  }
}

// ================= weight prep (identical to R11) =================
__global__ void kprep(const float* __restrict__ Wih, const float* __restrict__ b_ih,
                      const float* __restrict__ b_hh, const float* __restrict__ Wt,
                      const float* __restrict__ bt_ih, const float* __restrict__ bt_hh,
                      const float* __restrict__ wp, const float* __restrict__ F1,
                      const float* __restrict__ b1, float* __restrict__ wsf)
{
  int n = blockIdx.x*256 + threadIdx.x;
  if (n < 92416){
    int jp=n&3, lane=(n>>2)&63, rest=n>>8;
    int ks=rest%19, mt=rest/19;
    int m = mt*16 + (lane&15);
    int k = ks*32 + (lane>>4)*8 + 2*jp;
    float v0 = (m<300 && k  <600)? wp[m*600+k  ] : 0.f;
    float v1 = (m<300 && k+1<600)? wp[m*600+k+1] : 0.f;
    ((unsigned*)wsf)[OFF_WBF2+n] = ((unsigned)f2usr(v1)<<16) | f2usr(v0);
    return;
  }
  n -= 92416;
  if (n < 63232){
    int jp=n&3, lane=(n>>2)&63, rest=n>>8;
    int ks=rest%19, nt=rest/19;
    int col = nt*16 + (lane&15);
    int k = ks*32 + (lane>>4)*8 + 2*jp;
    float v0=0.f, v1=0.f;
    if (col<200){
      v0 = (k  <600)? F1[k*200+col]     : (k  ==600? b1[col] : 0.f);
      v1 = (k+1<600)? F1[(k+1)*200+col] : (k+1==600? b1[col] : 0.f);
    }
    ((unsigned*)wsf)[OFF_F1S+n] = ((unsigned)f2usr(v1)<<16) | f2usr(v0);
    return;
  }
  n -= 63232;
  if (n < 108000){
    int k=n/10800, r=n%10800, h=r/36, s=r%36;
    float v;
    if (s<33){
      int i=s/3, g=s%3;
      int G = h + (g==0?0:(g==1?600:900));
      v = Wih[(k*1200+G)*11 + i];
    } else {
      int g=s-33;
      int G = h + (g==0?0:(g==1?600:900));
      v = b_ih[k*1200+G] + b_hh[k*1200+G];
    }
    wsf[OFF_WIHP2+n] = v; return;
  }
  n -= 108000;
  if (n < 900){
    int h=n%300, g=n/300;
    int G = h + (g==0?0:(g==1?600:900));
    wsf[OFF_BTP+n] = bt_ih[G]+bt_hh[G]; return;
  }
  n -= 900;
  if (n < 3600){
    int h=n%300; int q=n/300; int g=q%3, e=q/3;
    int G = h + (g==0?0:(g==1?600:900));
    wsf[OFF_WTP+n] = Wt[G*4+e]; return;
  }
}

__global__ void kprep2(const float* __restrict__ DisM, float* __restrict__ wsf){
  if (threadIdx.x==0 && blockIdx.x==0){
    float m = DisM[0];
    for (int k=1;k<10;k++) m = fmaxf(m, DisM[k]);
    float e[10]; float s=0.f;
    for (int k=0;k<10;k++){ e[k]=__expf(DisM[k]-m); s+=e[k]; }
    float inv=1.0f/s; float sw=0.f;
    for (int k=0;k<10;k++){ float v=e[k]*inv; wsf[OFF_WA+k]=v; sw+=v; }
    wsf[OFF_SWA]=sw;
  }
}

extern "C" void kernel_launch(void* const* d_in, const int* in_sizes, int n_in,
                              void* d_out, int out_size, void* d_ws, size_t ws_size,
                              hipStream_t stream)
{
  const float* li     = (const float*)d_in[0];
  const float* labels = (const float*)d_in[1];
  const float* exs    = (const float*)d_in[2];
  const float* DisM   = (const float*)d_in[3];
  const float* AngleM = (const float*)d_in[4];
  const float* Wih    = (const float*)d_in[5];
  const float* b_ih   = (const float*)d_in[6];
  const float* b_hh   = (const float*)d_in[7];
  const float* Wt     = (const float*)d_in[8];
  const float* bt_ih  = (const float*)d_in[9];
  const float* bt_hh  = (const float*)d_in[10];
  const float* wp     = (const float*)d_in[11];
  const float* bp     = (const float*)d_in[12];
  const float* F1     = (const float*)d_in[13];
  const float* b1     = (const float*)d_in[14];
  const float* F2     = (const float*)d_in[15];
  const float* b2     = (const float*)d_in[16];
  const float* ff     = (const float*)d_in[17];
  const float* bff    = (const float*)d_in[18];
  const float* fuse1  = (const float*)d_in[19];
  const float* biasf  = (const float*)d_in[20];
  const float* Wout   = (const float*)d_in[21];
  const float* biasout= (const float*)d_in[22];
  const float* a      = (const float*)d_in[23];
  float* wsf = (float*)d_ws;
  float* outp = (float*)d_out;
  unsigned* con1u = (unsigned*)((char*)d_ws + CON1_BYTE);
  u16* cong = (u16*)((char*)d_ws + CONG_BYTE);

  if (ws_size < WS_MIN_BYTES) return;  // proven available (R4 PATH1 ran)

  kprep<<<dim3(1048), dim3(256), 0, stream>>>(Wih,b_ih,b_hh,Wt,bt_ih,bt_hh,wp,F1,b1,wsf);
  kprep2<<<dim3(1), dim3(64), 0, stream>>>(DisM, wsf);
  if (ws_size >= WS_SPLIT_BYTES){
    kern_cells<<<dim3(256,32), NTHR, 0, stream>>>(li, wsf, cong);
    kern_main_split<<<dim3(256,32), NTHR, 0, stream>>>(li, exs, AngleM, bp, F2, b2,
                                                       wsf, con1u, wsf + OFF_SM, cong);
  } else {
    kern_main_mono<<<dim3(256,32), NTHR, 0, stream>>>(li, exs, AngleM, bp, F2, b2,
                                                      wsf, con1u, wsf + OFF_SM);
  }
  kern_final<<<dim3(128,32), NTHR, 0, stream>>>(li, labels, ff, bff, fuse1, biasf,
                                                Wout, biasout, a, wsf, con1u, outp);
}

// Round 13
// 748.699 us; speedup vs baseline: 1.0853x; 1.0853x over previous
//
#include <hip/hip_runtime.h>
#include <hip/hip_bf16.h>

// GCLSTM: B=512, T=32, H=300, K=10. f32 in/out.
// R13 = R12 with kern_cells restructured: block=(k,t,bhalf), thread=h.
// Table row (36 f32) loaded ONCE per thread (was once per 4 evals, scattered);
// x[256][11] in LDS read as wave-uniform broadcasts; stores h-coalesced into
// the same cong tile layout. kern_main_split / kern_final / kprep unchanged.
// ws >= 198.3MB proven by R12 (split path ran).

#define TB 2
#define NR 32             // cct rows (MFMA N)
#define NTHR 640          // 10 waves
#define NW 10
#define KP 616
#define TBF 4             // kern_final b-tile

// ws layout (u32 slots) — identical to R11/R12
#define OFF_SM    0         // softmax [32][10][512] f32          163840
#define OFF_WBF2  163840    // wp A-frags [mt19][ks19][lane64][4]  92416
#define OFF_F1S   256256    // F1 B-frags [nt13][ks19][lane64][4]  63232
#define OFF_WIHP2 319488    // cells [k10][h300][36] f32 (33-35=bias) 108000
#define OFF_BTP   427488    // g*300+h f32                           900
#define OFF_WTP   428388    // (e*3+g)*300+h f32                    3600
#define OFF_WA    431988    // softmax(DisM) f32                      10
#define OFF_SWA   431998    // sum(wA) f32                             1
#define BASE_U32  432000
#define CON1_BYTE ((size_t)BASE_U32 * 4)                  // 1,728,000
#define WS_MIN_BYTES (CON1_BYTE + (size_t)98304000)       // 100,032,000
#define CONG_BYTE  WS_MIN_BYTES                           // con_g right after con1u
#define WS_SPLIT_BYTES (CONG_BYTE + (size_t)98304000)     // 198,336,000 (proven fits)

typedef __attribute__((ext_vector_type(8))) short s16x8;
typedef __attribute__((ext_vector_type(4))) float f32x4;
typedef unsigned short u16;

__device__ __forceinline__ float sigf(float x){ return 1.0f/(1.0f+__expf(-x)); }
__device__ __forceinline__ float tanhf_(float x){ return 1.0f - 2.0f/(__expf(2.0f*x)+1.0f); }
__device__ __forceinline__ float bfu(u16 u){ return __uint_as_float(((unsigned)u)<<16); }
__device__ __forceinline__ u16 f2us(float f){ return (u16)(__float_as_uint(f)>>16); }
__device__ __forceinline__ u16 f2usr(float f){   // RNE bf16
  __hip_bfloat16 h = __float2bfloat16(f);
  return *(u16*)&h;
}

// ===== split path: cells once per (t,b,k,h); block=(k,t,bhalf), thread=h =====
__global__ __launch_bounds__(320,2) void kern_cells(
    const float* __restrict__ li, const float* wsf, u16* __restrict__ cong)
{
  __shared__ __align__(16) float xs[256][12];   // 12 KB; cols 11 = pad
  const int tid=threadIdx.x, k=blockIdx.x, t=blockIdx.y, bh=blockIdx.z;
  const int bbase = bh*256;
  for (int p=tid; p<256*11; p+=320){
    int b=p/11, i=p%11;
    xs[b][i] = li[(((size_t)(bbase+b)*32+t)*28+i)*10+k];
  }
  __syncthreads();
  const int h = tid;
  if (h < 300){
    const float4* Wp = (const float4*)(wsf + OFF_WIHP2 + (size_t)(k*300+h)*36);
    float f[36];
    #pragma unroll
    for (int q=0;q<9;q++){
      float4 v = Wp[q];
      f[4*q+0]=v.x; f[4*q+1]=v.y; f[4*q+2]=v.z; f[4*q+3]=v.w;
    }
    #pragma unroll 2
    for (int b=0;b<256;b++){
      const int bg = bbase+b;
      float ai=f[33], ag=f[34], ao=f[35];
      #pragma unroll
      for (int i=0;i<11;i++){
        float xv = xs[b][i];   // wave-uniform address -> LDS broadcast
        ai += f[3*i+0]*xv; ag += f[3*i+1]*xv; ao += f[3*i+2]*xv;
      }
      float hv = sigf(ao) * tanhf_( sigf(ai) * tanhf_(ag) );
      cong[ ((size_t)(t*256+(bg>>1))*20 + (bg&1)*10+k)*300 + h ] = f2usr(hv);
    }
  }
}

// ============ kern_main body shared by both paths via template ============
template<int SPLIT>
__device__ __forceinline__ void kern_main_body(
    const float* __restrict__ li, const float* __restrict__ exs,
    const float* __restrict__ AngleM, const float* __restrict__ bp,
    const float* __restrict__ F2, const float* __restrict__ b2,
    const float* wsf, unsigned* __restrict__ con1u, float* smg,
    const u16* __restrict__ cong)
{
  __shared__ __align__(16) u16 cct[NR][KP];   // 39,424 B
  __shared__ float xs[2][TB][11][10];
  __shared__ float xse[TB][2][10];
  __shared__ float exss[TB][4];
  __shared__ float wdP[NW][NR];
  __shared__ float wdL[NR];
  const int tid = threadIdx.x;
  const int t = blockIdx.y, bt = blockIdx.x, b0 = bt*TB;
  const int w = tid>>6, lane = tid&63, lo = lane&15, qd = lane>>4;

  // ---- P0 ----
  if (!SPLIT){
    for (int p=tid; p<2*TB*110; p+=NTHR){
      int half=p/(110*TB), r=p%(110*TB), b=r/110, q=r%110, i=q/10, k=q%10;
      int tp = half ? (t>0? t-1 : 0) : t;
      xs[half][b][i][k] = li[(((b0+b)*32+tp)*28+i)*10+k];
    }
  }
  for (int p=tid;p<TB*20;p+=NTHR){
    int b=p/20, r=p%20, rr=r/10, k=r%10;
    xse[b][rr][k] = li[(((b0+b)*32+t)*28 + (rr?10:8))*10 + k];
  }
  for (int p=tid;p<TB*4;p+=NTHR){
    int b=p/4, e=p%4;
    exss[b][e] = exs[((b0+b)*32+t)*4+e];
  }
  for (int p=tid; p<20*4; p+=NTHR){
    int n=p/4, c=p%4;
    ((unsigned*)&cct[n][600])[c] = 0u;
  }
  for (int p=tid; p<12*(KP/2); p+=NTHR){
    int n=20+p/(KP/2), c=p%(KP/2);
    ((unsigned*)&cct[n][0])[c] = 0u;
  }
  __syncthreads();

  // ---- P1: con(t) -> cols 0-299, con(t-1) -> cols 300-599 ----
  const int nh = (t==0)?1:2;
  if (SPLIT){
    for (int p=tid; p<nh*3000; p+=NTHR){
      int half=p/3000, r=p%3000, n=r/150, op=r%150;
      int tp = half? t-1 : t;
      unsigned v = ((const unsigned*)cong)[ ((size_t)(tp*256+bt)*20+n)*150 + op ];
      *(unsigned*)&cct[n][300*half + 2*op] = v;
    }
  } else {
    for (int pt=tid; pt<3000; pt+=NTHR){
      int k=pt/300, h=pt%300;
      const float4* Wp = (const float4*)(wsf + OFF_WIHP2 + (size_t)(k*300+h)*36);
      float f[36];
      #pragma unroll
      for (int q=0;q<9;q++){
        float4 v = Wp[q];
        f[4*q+0]=v.x; f[4*q+1]=v.y; f[4*q+2]=v.z; f[4*q+3]=v.w;
      }
      for (int half=0; half<nh; half++){
        #pragma unroll
        for (int b=0;b<TB;b++){
          float ai=f[33], ag=f[34], ao=f[35];
          #pragma unroll
          for (int i=0;i<11;i++){
            float xv = xs[half][b][i][k];
            ai += f[3*i+0]*xv; ag += f[3*i+1]*xv; ao += f[3*i+2]*xv;
          }
          float hv = sigf(ao) * tanhf_( sigf(ai) * tanhf_(ag) );
          cct[b*10+k][h+300*half] = f2usr(hv);
        }
      }
    }
  }
  __syncthreads();

  // ---- P2: wp-MFMA  D[o 304][n 32]; 2 Mtiles/wave, 2 Ntiles ----
  f32x4 acc[2][2];
  #pragma unroll
  for (int i=0;i<2;i++)
    #pragma unroll
    for (int nt=0;nt<2;nt++) acc[i][nt] = (f32x4){0.f,0.f,0.f,0.f};
  if (t>0){
    const u16* wbfA = (const u16*)((const unsigned*)wsf + OFF_WBF2);
    for (int ks=0; ks<19; ks++){
      const int kb = ks*32 + qd*8;
      s16x8 Bv[2];
      #pragma unroll
      for (int nt=0;nt<2;nt++)
        Bv[nt] = *(const s16x8*)&cct[nt*16+lo][kb];
      #pragma unroll
      for (int i=0;i<2;i++){
        int mt = w*2+i;
        if (mt<19){
          s16x8 Av = *(const s16x8*)(wbfA + ((size_t)(mt*19+ks)*64 + lane)*8);
          #pragma unroll
          for (int nt=0;nt<2;nt++)
            acc[i][nt] = __builtin_amdgcn_mfma_f32_16x16x32_bf16(Av, Bv[nt], acc[i][nt], 0,0,0);
        }
      }
    }
  }
  __syncthreads();

  // ---- P2b (t>0): epilogue transpose ----
  if (t>0){
    #pragma unroll
    for (int i=0;i<2;i++){
      int mt = w*2+i;
      if (mt<19 && (mt<18 || qd<3)){
        int ob = mt*16 + qd*4;
        float p0=bp[ob], p1=bp[ob+1], p2=bp[ob+2], p3=bp[ob+3];
        #pragma unroll
        for (int nt=0;nt<2;nt++){
          int n = nt*16+lo;
          float v0=acc[i][nt][0]+p0, v1=acc[i][nt][1]+p1,
                v2=acc[i][nt][2]+p2, v3=acc[i][nt][3]+p3;
          unsigned w0 = ((unsigned)f2us(v1>0.f?v1:0.f)<<16) | f2us(v0>0.f?v0:0.f);
          unsigned w1 = ((unsigned)f2us(v3>0.f?v3:0.f)<<16) | f2us(v2>0.f?v2:0.f);
          *(unsigned*)&cct[n][ob]   = w0;
          *(unsigned*)&cct[n][ob+2] = w1;
        }
      }
    }
  }
  // ---- P3: htarget -> hcat cols [300,600); col 600 = 1.0 ----
  for (int p=tid; p<TB*300; p+=NTHR){
    int b=p/300, o=p%300;
    float ai=0.f, ag=0.f, ao=0.f;
    #pragma unroll
    for (int e=0;e<4;e++){
      float xv = exss[b][e];
      ai += wsf[OFF_WTP+(e*3+0)*300+o]*xv;
      ag += wsf[OFF_WTP+(e*3+1)*300+o]*xv;
      ao += wsf[OFF_WTP+(e*3+2)*300+o]*xv;
    }
    ai += wsf[OFF_BTP+o]; ag += wsf[OFF_BTP+300+o]; ao += wsf[OFF_BTP+600+o];
    u16 u = f2usr( sigf(ao)*tanhf_(sigf(ai)*tanhf_(ag)) );
    #pragma unroll
    for (int k=0;k<10;k++) cct[b*10+k][300+o] = u;
  }
  for (int p=tid; p<20*4; p+=NTHR){
    int n=p/4, c=p%4;
    ((unsigned*)&cct[n][600])[c] = (c==0)? 0x00003f80u : 0u;
  }
  __syncthreads();

  // ---- P5: store con1 tile [n 20][o 300] coalesced ----
  for (int p=tid; p<TB*1500; p+=NTHR){
    int n=p/150, op=p%150;
    con1u[ ((size_t)(t*256+bt)*20 + n)*150 + op ] = *(const unsigned*)&cct[n][2*op];
  }

  // ---- P4: F1-MFMA  fc1[n 32][j 208]; 2 Mtiles, nt in {w, w+10} ----
  f32x4 acc2[2][2];
  #pragma unroll
  for (int mt=0;mt<2;mt++)
    #pragma unroll
    for (int j=0;j<2;j++) acc2[mt][j] = (f32x4){0.f,0.f,0.f,0.f};
  {
    const u16* f1s = (const u16*)((const unsigned*)wsf + OFF_F1S);
    for (int ks=0; ks<19; ks++){
      const int kb = ks*32 + qd*8;
      s16x8 Am[2];
      #pragma unroll
      for (int mt=0;mt<2;mt++)
        Am[mt] = *(const s16x8*)&cct[mt*16+lo][kb];
      #pragma unroll
      for (int j=0;j<2;j++){
        int nt = w + j*NW;
        if (nt<13){
          s16x8 Bf = *(const s16x8*)(f1s + ((size_t)(nt*19+ks)*64 + lane)*8);
          #pragma unroll
          for (int mt=0;mt<2;mt++)
            acc2[mt][j] = __builtin_amdgcn_mfma_f32_16x16x32_bf16(Am[mt], Bf, acc2[mt][j], 0,0,0);
        }
      }
    }
  }
  {
    float f2c[2];
    #pragma unroll
    for (int j=0;j<2;j++){
      int nt = w + j*NW;
      int jj = nt*16+lo;
      f2c[j] = (nt<13 && jj<200)? F2[jj] : 0.f;
    }
    #pragma unroll
    for (int mt=0;mt<2;mt++)
      #pragma unroll
      for (int r=0;r<4;r++){
        float s = 0.f;
        #pragma unroll
        for (int j=0;j<2;j++){
          float v = acc2[mt][j][r];
          s += (v>0.f? v:0.f) * f2c[j];
        }
        s += __shfl_xor(s,1,64); s += __shfl_xor(s,2,64);
        s += __shfl_xor(s,4,64); s += __shfl_xor(s,8,64);
        if (lo==0) wdP[w][mt*16+qd*4+r] = s;
      }
  }
  __syncthreads();
  if (tid<TB*10){
    int n=tid, b=n/10, k=n%10;
    float v = 0.f;
    #pragma unroll
    for (int ww=0;ww<NW;ww++) v += wdP[ww][n];
    float ang = fabsf(xse[b][1][k]-AngleM[k]) * (1.0f/360.0f);
    v += xse[b][0][k]*F2[200] + ang*F2[201] + b2[0];
    wdL[n] = v>0.f? v : 0.f;
  }
  __syncthreads();
  if (tid<TB){
    int b=tid;
    float m = wdL[b*10];
    #pragma unroll
    for (int k=1;k<10;k++) m = fmaxf(m, wdL[b*10+k]);
    float e[10]; float s=0.f;
    #pragma unroll
    for (int k=0;k<10;k++){ e[k]=__expf(wdL[b*10+k]-m); s+=e[k]; }
    float inv = 1.0f/s;
    #pragma unroll
    for (int k=0;k<10;k++) smg[t*5120 + k*512 + b0+b] = e[k]*inv;
  }
}

__global__ __launch_bounds__(NTHR,2) void kern_main_mono(
    const float* __restrict__ li, const float* __restrict__ exs,
    const float* __restrict__ AngleM, const float* __restrict__ bp,
    const float* __restrict__ F2, const float* __restrict__ b2,
    const float* wsf, unsigned* __restrict__ con1u, float* smg)
{
  kern_main_body<0>(li,exs,AngleM,bp,F2,b2,wsf,con1u,smg,(const u16*)nullptr);
}

__global__ __launch_bounds__(NTHR,2) void kern_main_split(
    const float* __restrict__ li, const float* __restrict__ exs,
    const float* __restrict__ AngleM, const float* __restrict__ bp,
    const float* __restrict__ F2, const float* __restrict__ b2,
    const float* wsf, unsigned* __restrict__ con1u, float* smg,
    const u16* __restrict__ cong)
{
  kern_main_body<1>(li,exs,AngleM,bp,F2,b2,wsf,con1u,smg,cong);
}

// ====== final: gather scramble, fuse, preds (+ labels copy fused); TBF=4 ======
__global__ __launch_bounds__(NTHR,3) void kern_final(
    const float* __restrict__ li, const float* __restrict__ labels,
    const float* __restrict__ ff, const float* __restrict__ bff,
    const float* __restrict__ fuse1, const float* __restrict__ biasf,
    const float* __restrict__ Wout, const float* __restrict__ biasout,
    const float* __restrict__ a, const float* wsf,
    const unsigned* __restrict__ con1u, float* __restrict__ outp)
{
  __shared__ unsigned conTu[40][152];
  __shared__ float xs17[TBF][17][10];
  __shared__ float cats[TBF][300];
  __shared__ float wa3s[TBF][10];
  __shared__ float dss[TBF][17];
  __shared__ float wAs[10];
  __shared__ float fup1[8][64], fup2[8][64];
  const int tid=threadIdx.x, t=blockIdx.y, bt=blockIdx.x, b0=bt*TBF;
  if (tid>=NTHR-TBF && tid<NTHR){
    int b = tid-(NTHR-TBF);
    outp[16384 + t*512 + b0+b] = labels[(b0+b)*32+t];
  }
  for (int p=tid;p<TBF*170;p+=NTHR){
    int b=p/170, r=p%170, f=r/10, k=r%10;
    xs17[b][f][k] = li[(((b0+b)*32+t)*28 + 11+f)*10 + k];
  }
  if (tid<10) wAs[tid] = wsf[OFF_WA+tid];
  for (int p=tid;p<6000;p+=NTHR){
    int n4=p/150, op=p%150;
    int b=n4/10, k=n4%10, bg=b0+b;
    conTu[n4][op] = con1u[ ((size_t)(t*256+(bg>>1))*20 + (bg&1)*10 + k)*150 + op ];
  }
  __syncthreads();
  for (int p=tid;p<TBF*10;p+=NTHR){
    int b=p/10, k=p%10;
    int g = (b0+b)*10+k;
    wa3s[b][k] = wsf[OFF_SM + t*5120 + (g>>9)*512 + (g&511)];
  }
  for (int p=tid;p<TBF*17;p+=NTHR){
    int b=p/17, f=p%17; float s=0.f;
    #pragma unroll
    for (int k=0;k<10;k++) s += xs17[b][f][k]*wAs[k];
    dss[b][f]=s;
  }
  __syncthreads();
  const u16* conT = (const u16*)conTu;
  for (int p=tid;p<TBF*300;p+=NTHR){
    int b=p/300, h=p%300;
    float s=0.f;
    #pragma unroll
    for (int k=0;k<10;k++)
      s += bfu(conT[(b*10+k)*304 + h]) * wa3s[b][k];
    cats[b][h]=s;
  }
  __syncthreads();
  const int w = tid>>6, lane = tid&63;
  const int o1 = lane;
  const bool o2v = lane<36;
  const int o2 = o2v ? (64+lane) : 99;
  if (w<8){
    int b=w>>1, half=w&1;
    float fu1 = half? 0.f : biasf[o1];
    float fu2 = half? 0.f : biasf[o2];
    const int hb = half*150;
    for (int h=hb; h<hb+150; h++){
      float cv = cats[b][h];
      fu1 += cv*fuse1[h*100+o1];
      fu2 += cv*fuse1[h*100+o2];
    }
    fup1[w][lane]=fu1; fup2[w][lane]=fu2;
  }
  __syncthreads();
  if (w<TBF){
    const int b=w, bg=b0+b;
    const float aa = a[0], swa = wsf[OFF_SWA];
    float fu1 = fup1[2*b][lane] + fup1[2*b+1][lane];
    float fu2 = fup2[2*b][lane] + fup2[2*b+1][lane];
    float fd1 = bff[o1]*swa, fd2 = bff[o2]*swa;
    #pragma unroll
    for (int f=0;f<17;f++){
      float dv = dss[b][f];
      fd1 += ff[o1*17+f]*dv;
      fd2 += ff[o2*17+f]*dv;
    }
    float v = (aa*fu1+(1.f-aa)*fd1)*Wout[o1];
    if (o2v) v += (aa*fu2+(1.f-aa)*fd2)*Wout[o2];
    #pragma unroll
    for (int off=32;off>=1;off>>=1) v += __shfl_xor(v,off,64);
    if (lane==0) outp[t*512+bg] = v + biasout[0];
  }
}

// ================= weight prep (identical to R11/R12) =================
__global__ void kprep(const float* __restrict__ Wih, const float* __restrict__ b_ih,
                      const float* __restrict__ b_hh, const float* __restrict__ Wt,
                      const float* __restrict__ bt_ih, const float* __restrict__ bt_hh,
                      const float* __restrict__ wp, const float* __restrict__ F1,
                      const float* __restrict__ b1, float* __restrict__ wsf)
{
  int n = blockIdx.x*256 + threadIdx.x;
  if (n < 92416){
    int jp=n&3, lane=(n>>2)&63, rest=n>>8;
    int ks=rest%19, mt=rest/19;
    int m = mt*16 + (lane&15);
    int k = ks*32 + (lane>>4)*8 + 2*jp;
    float v0 = (m<300 && k  <600)? wp[m*600+k  ] : 0.f;
    float v1 = (m<300 && k+1<600)? wp[m*600+k+1] : 0.f;
    ((unsigned*)wsf)[OFF_WBF2+n] = ((unsigned)f2usr(v1)<<16) | f2usr(v0);
    return;
  }
  n -= 92416;
  if (n < 63232){
    int jp=n&3, lane=(n>>2)&63, rest=n>>8;
    int ks=rest%19, nt=rest/19;
    int col = nt*16 + (lane&15);
    int k = ks*32 + (lane>>4)*8 + 2*jp;
    float v0=0.f, v1=0.f;
    if (col<200){
      v0 = (k  <600)? F1[k*200+col]     : (k  ==600? b1[col] : 0.f);
      v1 = (k+1<600)? F1[(k+1)*200+col] : (k+1==600? b1[col] : 0.f);
    }
    ((unsigned*)wsf)[OFF_F1S+n] = ((unsigned)f2usr(v1)<<16) | f2usr(v0);
    return;
  }
  n -= 63232;
  if (n < 108000){
    int k=n/10800, r=n%10800, h=r/36, s=r%36;
    float v;
    if (s<33){
      int i=s/3, g=s%3;
      int G = h + (g==0?0:(g==1?600:900));
      v = Wih[(k*1200+G)*11 + i];
    } else {
      int g=s-33;
      int G = h + (g==0?0:(g==1?600:900));
      v = b_ih[k*1200+G] + b_hh[k*1200+G];
    }
    wsf[OFF_WIHP2+n] = v; return;
  }
  n -= 108000;
  if (n < 900){
    int h=n%300, g=n/300;
    int G = h + (g==0?0:(g==1?600:900));
    wsf[OFF_BTP+n] = bt_ih[G]+bt_hh[G]; return;
  }
  n -= 900;
  if (n < 3600){
    int h=n%300; int q=n/300; int g=q%3, e=q/3;
    int G = h + (g==0?0:(g==1?600:900));
    wsf[OFF_WTP+n] = Wt[G*4+e]; return;
  }
}

__global__ void kprep2(const float* __restrict__ DisM, float* __restrict__ wsf){
  if (threadIdx.x==0 && blockIdx.x==0){
    float m = DisM[0];
    for (int k=1;k<10;k++) m = fmaxf(m, DisM[k]);
    float e[10]; float s=0.f;
    for (int k=0;k<10;k++){ e[k]=__expf(DisM[k]-m); s+=e[k]; }
    float inv=1.0f/s; float sw=0.f;
    for (int k=0;k<10;k++){ float v=e[k]*inv; wsf[OFF_WA+k]=v; sw+=v; }
    wsf[OFF_SWA]=sw;
  }
}

extern "C" void kernel_launch(void* const* d_in, const int* in_sizes, int n_in,
                              void* d_out, int out_size, void* d_ws, size_t ws_size,
                              hipStream_t stream)
{
  const float* li     = (const float*)d_in[0];
  const float* labels = (const float*)d_in[1];
  const float* exs    = (const float*)d_in[2];
  const float* DisM   = (const float*)d_in[3];
  const float* AngleM = (const float*)d_in[4];
  const float* Wih    = (const float*)d_in[5];
  const float* b_ih   = (const float*)d_in[6];
  const float* b_hh   = (const float*)d_in[7];
  const float* Wt     = (const float*)d_in[8];
  const float* bt_ih  = (const float*)d_in[9];
  const float* bt_hh  = (const float*)d_in[10];
  const float* wp     = (const float*)d_in[11];
  const float* bp     = (const float*)d_in[12];
  const float* F1     = (const float*)d_in[13];
  const float* b1     = (const float*)d_in[14];
  const float* F2     = (const float*)d_in[15];
  const float* b2     = (const float*)d_in[16];
  const float* ff     = (const float*)d_in[17];
  const float* bff    = (const float*)d_in[18];
  const float* fuse1  = (const float*)d_in[19];
  const float* biasf  = (const float*)d_in[20];
  const float* Wout   = (const float*)d_in[21];
  const float* biasout= (const float*)d_in[22];
  const float* a      = (const float*)d_in[23];
  float* wsf = (float*)d_ws;
  float* outp = (float*)d_out;
  unsigned* con1u = (unsigned*)((char*)d_ws + CON1_BYTE);
  u16* cong = (u16*)((char*)d_ws + CONG_BYTE);

  if (ws_size < WS_MIN_BYTES) return;

  kprep<<<dim3(1048), dim3(256), 0, stream>>>(Wih,b_ih,b_hh,Wt,bt_ih,bt_hh,wp,F1,b1,wsf);
  kprep2<<<dim3(1), dim3(64), 0, stream>>>(DisM, wsf);
  if (ws_size >= WS_SPLIT_BYTES){
    kern_cells<<<dim3(10,32,2), dim3(320), 0, stream>>>(li, wsf, cong);
    kern_main_split<<<dim3(256,32), NTHR, 0, stream>>>(li, exs, AngleM, bp, F2, b2,
                                                       wsf, con1u, wsf + OFF_SM, cong);
  } else {
    kern_main_mono<<<dim3(256,32), NTHR, 0, stream>>>(li, exs, AngleM, bp, F2, b2,
                                                      wsf, con1u, wsf + OFF_SM);
  }
  kern_final<<<dim3(128,32), NTHR, 0, stream>>>(li, labels, ff, bff, fuse1, biasf,
                                                Wout, biasout, a, wsf, con1u, outp);
}

// Round 14
// 637.234 us; speedup vs baseline: 1.2752x; 1.1749x over previous
//
#include <hip/hip_runtime.h>
#include <hip/hip_bf16.h>

// GCLSTM: B=512, T=32, H=300, K=10. f32 in/out.
// R14 = R13 with kern_cells fixed: (1) v_rcp_f32 via __builtin_amdgcn_rcpf
// replaces IEEE division in sigf/tanhf_ (4 divs/eval = ~40 extra VALU inst
// under default FP rules — the 4x-over-model cost); (2) grid (10,32,8) =
// 2560 blocks, 64 b each (was 640 x 256b: 2.5/CU, imbalanced); (3) linear
// cong addressing (10*bg identity). kern_main_split/kern_final/kprep frozen.
// ws >= 198.3MB proven by R12 (split path ran).

#define TB 2
#define NR 32             // cct rows (MFMA N)
#define NTHR 640          // 10 waves
#define NW 10
#define KP 616
#define TBF 4             // kern_final b-tile

// ws layout (u32 slots) — identical to R11/R12/R13
#define OFF_SM    0         // softmax [32][10][512] f32          163840
#define OFF_WBF2  163840    // wp A-frags [mt19][ks19][lane64][4]  92416
#define OFF_F1S   256256    // F1 B-frags [nt13][ks19][lane64][4]  63232
#define OFF_WIHP2 319488    // cells [k10][h300][36] f32 (33-35=bias) 108000
#define OFF_BTP   427488    // g*300+h f32                           900
#define OFF_WTP   428388    // (e*3+g)*300+h f32                    3600
#define OFF_WA    431988    // softmax(DisM) f32                      10
#define OFF_SWA   431998    // sum(wA) f32                             1
#define BASE_U32  432000
#define CON1_BYTE ((size_t)BASE_U32 * 4)                  // 1,728,000
#define WS_MIN_BYTES (CON1_BYTE + (size_t)98304000)       // 100,032,000
#define CONG_BYTE  WS_MIN_BYTES                           // con_g right after con1u
#define WS_SPLIT_BYTES (CONG_BYTE + (size_t)98304000)     // 198,336,000 (proven fits)

typedef __attribute__((ext_vector_type(8))) short s16x8;
typedef __attribute__((ext_vector_type(4))) float f32x4;
typedef unsigned short u16;

__device__ __forceinline__ float rcpf(float x){ return __builtin_amdgcn_rcpf(x); }
__device__ __forceinline__ float sigf(float x){ return rcpf(1.0f+__expf(-x)); }
__device__ __forceinline__ float tanhf_(float x){ return 1.0f - 2.0f*rcpf(__expf(2.0f*x)+1.0f); }
__device__ __forceinline__ float bfu(u16 u){ return __uint_as_float(((unsigned)u)<<16); }
__device__ __forceinline__ u16 f2us(float f){ return (u16)(__float_as_uint(f)>>16); }
__device__ __forceinline__ u16 f2usr(float f){   // RNE bf16
  __hip_bfloat16 h = __float2bfloat16(f);
  return *(u16*)&h;
}

// ===== split path: cells once per (t,b,k,h); block=(k,t,b64), thread=h =====
__global__ __launch_bounds__(320,4) void kern_cells(
    const float* __restrict__ li, const float* wsf, u16* __restrict__ cong)
{
  __shared__ __align__(16) float xs[64][12];   // 3 KB; col 11 = pad
  const int tid=threadIdx.x, k=blockIdx.x, t=blockIdx.y, bh=blockIdx.z;
  const int bbase = bh*64;
  for (int p=tid; p<64*11; p+=320){
    int b=p/11, i=p%11;
    xs[b][i] = li[(((size_t)(bbase+b)*32+t)*28+i)*10+k];
  }
  __syncthreads();
  const int h = tid;
  if (h < 300){
    const float4* Wp = (const float4*)(wsf + OFF_WIHP2 + (size_t)(k*300+h)*36);
    float f[36];
    #pragma unroll
    for (int q=0;q<9;q++){
      float4 v = Wp[q];
      f[4*q+0]=v.x; f[4*q+1]=v.y; f[4*q+2]=v.z; f[4*q+3]=v.w;
    }
    // cong layout identity: ((bg>>1)*20+(bg&1)*10+k) == bg*10+k
    u16* out = cong + ((size_t)t*5120 + (size_t)bbase*10 + k)*300 + h;
    #pragma unroll 4
    for (int b=0;b<64;b++){
      float ai=f[33], ag=f[34], ao=f[35];
      #pragma unroll
      for (int i=0;i<11;i++){
        float xv = xs[b][i];   // wave-uniform address -> LDS broadcast
        ai += f[3*i+0]*xv; ag += f[3*i+1]*xv; ao += f[3*i+2]*xv;
      }
      float hv = sigf(ao) * tanhf_( sigf(ai) * tanhf_(ag) );
      out[(size_t)b*3000] = f2usr(hv);
    }
  }
}

// ============ kern_main body shared by both paths via template ============
template<int SPLIT>
__device__ __forceinline__ void kern_main_body(
    const float* __restrict__ li, const float* __restrict__ exs,
    const float* __restrict__ AngleM, const float* __restrict__ bp,
    const float* __restrict__ F2, const float* __restrict__ b2,
    const float* wsf, unsigned* __restrict__ con1u, float* smg,
    const u16* __restrict__ cong)
{
  __shared__ __align__(16) u16 cct[NR][KP];   // 39,424 B
  __shared__ float xs[2][TB][11][10];
  __shared__ float xse[TB][2][10];
  __shared__ float exss[TB][4];
  __shared__ float wdP[NW][NR];
  __shared__ float wdL[NR];
  const int tid = threadIdx.x;
  const int t = blockIdx.y, bt = blockIdx.x, b0 = bt*TB;
  const int w = tid>>6, lane = tid&63, lo = lane&15, qd = lane>>4;

  // ---- P0 ----
  if (!SPLIT){
    for (int p=tid; p<2*TB*110; p+=NTHR){
      int half=p/(110*TB), r=p%(110*TB), b=r/110, q=r%110, i=q/10, k=q%10;
      int tp = half ? (t>0? t-1 : 0) : t;
      xs[half][b][i][k] = li[(((b0+b)*32+tp)*28+i)*10+k];
    }
  }
  for (int p=tid;p<TB*20;p+=NTHR){
    int b=p/20, r=p%20, rr=r/10, k=r%10;
    xse[b][rr][k] = li[(((b0+b)*32+t)*28 + (rr?10:8))*10 + k];
  }
  for (int p=tid;p<TB*4;p+=NTHR){
    int b=p/4, e=p%4;
    exss[b][e] = exs[((b0+b)*32+t)*4+e];
  }
  for (int p=tid; p<20*4; p+=NTHR){
    int n=p/4, c=p%4;
    ((unsigned*)&cct[n][600])[c] = 0u;
  }
  for (int p=tid; p<12*(KP/2); p+=NTHR){
    int n=20+p/(KP/2), c=p%(KP/2);
    ((unsigned*)&cct[n][0])[c] = 0u;
  }
  __syncthreads();

  // ---- P1: con(t) -> cols 0-299, con(t-1) -> cols 300-599 ----
  const int nh = (t==0)?1:2;
  if (SPLIT){
    for (int p=tid; p<nh*3000; p+=NTHR){
      int half=p/3000, r=p%3000, n=r/150, op=r%150;
      int tp = half? t-1 : t;
      unsigned v = ((const unsigned*)cong)[ ((size_t)(tp*256+bt)*20+n)*150 + op ];
      *(unsigned*)&cct[n][300*half + 2*op] = v;
    }
  } else {
    for (int pt=tid; pt<3000; pt+=NTHR){
      int k=pt/300, h=pt%300;
      const float4* Wp = (const float4*)(wsf + OFF_WIHP2 + (size_t)(k*300+h)*36);
      float f[36];
      #pragma unroll
      for (int q=0;q<9;q++){
        float4 v = Wp[q];
        f[4*q+0]=v.x; f[4*q+1]=v.y; f[4*q+2]=v.z; f[4*q+3]=v.w;
      }
      for (int half=0; half<nh; half++){
        #pragma unroll
        for (int b=0;b<TB;b++){
          float ai=f[33], ag=f[34], ao=f[35];
          #pragma unroll
          for (int i=0;i<11;i++){
            float xv = xs[half][b][i][k];
            ai += f[3*i+0]*xv; ag += f[3*i+1]*xv; ao += f[3*i+2]*xv;
          }
          float hv = sigf(ao) * tanhf_( sigf(ai) * tanhf_(ag) );
          cct[b*10+k][h+300*half] = f2usr(hv);
        }
      }
    }
  }
  __syncthreads();

  // ---- P2: wp-MFMA  D[o 304][n 32]; 2 Mtiles/wave, 2 Ntiles ----
  f32x4 acc[2][2];
  #pragma unroll
  for (int i=0;i<2;i++)
    #pragma unroll
    for (int nt=0;nt<2;nt++) acc[i][nt] = (f32x4){0.f,0.f,0.f,0.f};
  if (t>0){
    const u16* wbfA = (const u16*)((const unsigned*)wsf + OFF_WBF2);
    for (int ks=0; ks<19; ks++){
      const int kb = ks*32 + qd*8;
      s16x8 Bv[2];
      #pragma unroll
      for (int nt=0;nt<2;nt++)
        Bv[nt] = *(const s16x8*)&cct[nt*16+lo][kb];
      #pragma unroll
      for (int i=0;i<2;i++){
        int mt = w*2+i;
        if (mt<19){
          s16x8 Av = *(const s16x8*)(wbfA + ((size_t)(mt*19+ks)*64 + lane)*8);
          #pragma unroll
          for (int nt=0;nt<2;nt++)
            acc[i][nt] = __builtin_amdgcn_mfma_f32_16x16x32_bf16(Av, Bv[nt], acc[i][nt], 0,0,0);
        }
      }
    }
  }
  __syncthreads();

  // ---- P2b (t>0): epilogue transpose ----
  if (t>0){
    #pragma unroll
    for (int i=0;i<2;i++){
      int mt = w*2+i;
      if (mt<19 && (mt<18 || qd<3)){
        int ob = mt*16 + qd*4;
        float p0=bp[ob], p1=bp[ob+1], p2=bp[ob+2], p3=bp[ob+3];
        #pragma unroll
        for (int nt=0;nt<2;nt++){
          int n = nt*16+lo;
          float v0=acc[i][nt][0]+p0, v1=acc[i][nt][1]+p1,
                v2=acc[i][nt][2]+p2, v3=acc[i][nt][3]+p3;
          unsigned w0 = ((unsigned)f2us(v1>0.f?v1:0.f)<<16) | f2us(v0>0.f?v0:0.f);
          unsigned w1 = ((unsigned)f2us(v3>0.f?v3:0.f)<<16) | f2us(v2>0.f?v2:0.f);
          *(unsigned*)&cct[n][ob]   = w0;
          *(unsigned*)&cct[n][ob+2] = w1;
        }
      }
    }
  }
  // ---- P3: htarget -> hcat cols [300,600); col 600 = 1.0 ----
  for (int p=tid; p<TB*300; p+=NTHR){
    int b=p/300, o=p%300;
    float ai=0.f, ag=0.f, ao=0.f;
    #pragma unroll
    for (int e=0;e<4;e++){
      float xv = exss[b][e];
      ai += wsf[OFF_WTP+(e*3+0)*300+o]*xv;
      ag += wsf[OFF_WTP+(e*3+1)*300+o]*xv;
      ao += wsf[OFF_WTP+(e*3+2)*300+o]*xv;
    }
    ai += wsf[OFF_BTP+o]; ag += wsf[OFF_BTP+300+o]; ao += wsf[OFF_BTP+600+o];
    u16 u = f2usr( sigf(ao)*tanhf_(sigf(ai)*tanhf_(ag)) );
    #pragma unroll
    for (int k=0;k<10;k++) cct[b*10+k][300+o] = u;
  }
  for (int p=tid; p<20*4; p+=NTHR){
    int n=p/4, c=p%4;
    ((unsigned*)&cct[n][600])[c] = (c==0)? 0x00003f80u : 0u;
  }
  __syncthreads();

  // ---- P5: store con1 tile [n 20][o 300] coalesced ----
  for (int p=tid; p<TB*1500; p+=NTHR){
    int n=p/150, op=p%150;
    con1u[ ((size_t)(t*256+bt)*20 + n)*150 + op ] = *(const unsigned*)&cct[n][2*op];
  }

  // ---- P4: F1-MFMA  fc1[n 32][j 208]; 2 Mtiles, nt in {w, w+10} ----
  f32x4 acc2[2][2];
  #pragma unroll
  for (int mt=0;mt<2;mt++)
    #pragma unroll
    for (int j=0;j<2;j++) acc2[mt][j] = (f32x4){0.f,0.f,0.f,0.f};
  {
    const u16* f1s = (const u16*)((const unsigned*)wsf + OFF_F1S);
    for (int ks=0; ks<19; ks++){
      const int kb = ks*32 + qd*8;
      s16x8 Am[2];
      #pragma unroll
      for (int mt=0;mt<2;mt++)
        Am[mt] = *(const s16x8*)&cct[mt*16+lo][kb];
      #pragma unroll
      for (int j=0;j<2;j++){
        int nt = w + j*NW;
        if (nt<13){
          s16x8 Bf = *(const s16x8*)(f1s + ((size_t)(nt*19+ks)*64 + lane)*8);
          #pragma unroll
          for (int mt=0;mt<2;mt++)
            acc2[mt][j] = __builtin_amdgcn_mfma_f32_16x16x32_bf16(Am[mt], Bf, acc2[mt][j], 0,0,0);
        }
      }
    }
  }
  {
    float f2c[2];
    #pragma unroll
    for (int j=0;j<2;j++){
      int nt = w + j*NW;
      int jj = nt*16+lo;
      f2c[j] = (nt<13 && jj<200)? F2[jj] : 0.f;
    }
    #pragma unroll
    for (int mt=0;mt<2;mt++)
      #pragma unroll
      for (int r=0;r<4;r++){
        float s = 0.f;
        #pragma unroll
        for (int j=0;j<2;j++){
          float v = acc2[mt][j][r];
          s += (v>0.f? v:0.f) * f2c[j];
        }
        s += __shfl_xor(s,1,64); s += __shfl_xor(s,2,64);
        s += __shfl_xor(s,4,64); s += __shfl_xor(s,8,64);
        if (lo==0) wdP[w][mt*16+qd*4+r] = s;
      }
  }
  __syncthreads();
  if (tid<TB*10){
    int n=tid, b=n/10, k=n%10;
    float v = 0.f;
    #pragma unroll
    for (int ww=0;ww<NW;ww++) v += wdP[ww][n];
    float ang = fabsf(xse[b][1][k]-AngleM[k]) * (1.0f/360.0f);
    v += xse[b][0][k]*F2[200] + ang*F2[201] + b2[0];
    wdL[n] = v>0.f? v : 0.f;
  }
  __syncthreads();
  if (tid<TB){
    int b=tid;
    float m = wdL[b*10];
    #pragma unroll
    for (int k=1;k<10;k++) m = fmaxf(m, wdL[b*10+k]);
    float e[10]; float s=0.f;
    #pragma unroll
    for (int k=0;k<10;k++){ e[k]=__expf(wdL[b*10+k]-m); s+=e[k]; }
    float inv = rcpf(s);
    #pragma unroll
    for (int k=0;k<10;k++) smg[t*5120 + k*512 + b0+b] = e[k]*inv;
  }
}

__global__ __launch_bounds__(NTHR,2) void kern_main_mono(
    const float* __restrict__ li, const float* __restrict__ exs,
    const float* __restrict__ AngleM, const float* __restrict__ bp,
    const float* __restrict__ F2, const float* __restrict__ b2,
    const float* wsf, unsigned* __restrict__ con1u, float* smg)
{
  kern_main_body<0>(li,exs,AngleM,bp,F2,b2,wsf,con1u,smg,(const u16*)nullptr);
}

__global__ __launch_bounds__(NTHR,2) void kern_main_split(
    const float* __restrict__ li, const float* __restrict__ exs,
    const float* __restrict__ AngleM, const float* __restrict__ bp,
    const float* __restrict__ F2, const float* __restrict__ b2,
    const float* wsf, unsigned* __restrict__ con1u, float* smg,
    const u16* __restrict__ cong)
{
  kern_main_body<1>(li,exs,AngleM,bp,F2,b2,wsf,con1u,smg,cong);
}

// ====== final: gather scramble, fuse, preds (+ labels copy fused); TBF=4 ======
__global__ __launch_bounds__(NTHR,3) void kern_final(
    const float* __restrict__ li, const float* __restrict__ labels,
    const float* __restrict__ ff, const float* __restrict__ bff,
    const float* __restrict__ fuse1, const float* __restrict__ biasf,
    const float* __restrict__ Wout, const float* __restrict__ biasout,
    const float* __restrict__ a, const float* wsf,
    const unsigned* __restrict__ con1u, float* __restrict__ outp)
{
  __shared__ unsigned conTu[40][152];
  __shared__ float xs17[TBF][17][10];
  __shared__ float cats[TBF][300];
  __shared__ float wa3s[TBF][10];
  __shared__ float dss[TBF][17];
  __shared__ float wAs[10];
  __shared__ float fup1[8][64], fup2[8][64];
  const int tid=threadIdx.x, t=blockIdx.y, bt=blockIdx.x, b0=bt*TBF;
  if (tid>=NTHR-TBF && tid<NTHR){
    int b = tid-(NTHR-TBF);
    outp[16384 + t*512 + b0+b] = labels[(b0+b)*32+t];
  }
  for (int p=tid;p<TBF*170;p+=NTHR){
    int b=p/170, r=p%170, f=r/10, k=r%10;
    xs17[b][f][k] = li[(((b0+b)*32+t)*28 + 11+f)*10 + k];
  }
  if (tid<10) wAs[tid] = wsf[OFF_WA+tid];
  for (int p=tid;p<6000;p+=NTHR){
    int n4=p/150, op=p%150;
    int b=n4/10, k=n4%10, bg=b0+b;
    conTu[n4][op] = con1u[ ((size_t)(t*256+(bg>>1))*20 + (bg&1)*10 + k)*150 + op ];
  }
  __syncthreads();
  for (int p=tid;p<TBF*10;p+=NTHR){
    int b=p/10, k=p%10;
    int g = (b0+b)*10+k;
    wa3s[b][k] = wsf[OFF_SM + t*5120 + (g>>9)*512 + (g&511)];
  }
  for (int p=tid;p<TBF*17;p+=NTHR){
    int b=p/17, f=p%17; float s=0.f;
    #pragma unroll
    for (int k=0;k<10;k++) s += xs17[b][f][k]*wAs[k];
    dss[b][f]=s;
  }
  __syncthreads();
  const u16* conT = (const u16*)conTu;
  for (int p=tid;p<TBF*300;p+=NTHR){
    int b=p/300, h=p%300;
    float s=0.f;
    #pragma unroll
    for (int k=0;k<10;k++)
      s += bfu(conT[(b*10+k)*304 + h]) * wa3s[b][k];
    cats[b][h]=s;
  }
  __syncthreads();
  const int w = tid>>6, lane = tid&63;
  const int o1 = lane;
  const bool o2v = lane<36;
  const int o2 = o2v ? (64+lane) : 99;
  if (w<8){
    int b=w>>1, half=w&1;
    float fu1 = half? 0.f : biasf[o1];
    float fu2 = half? 0.f : biasf[o2];
    const int hb = half*150;
    for (int h=hb; h<hb+150; h++){
      float cv = cats[b][h];
      fu1 += cv*fuse1[h*100+o1];
      fu2 += cv*fuse1[h*100+o2];
    }
    fup1[w][lane]=fu1; fup2[w][lane]=fu2;
  }
  __syncthreads();
  if (w<TBF){
    const int b=w, bg=b0+b;
    const float aa = a[0], swa = wsf[OFF_SWA];
    float fu1 = fup1[2*b][lane] + fup1[2*b+1][lane];
    float fu2 = fup2[2*b][lane] + fup2[2*b+1][lane];
    float fd1 = bff[o1]*swa, fd2 = bff[o2]*swa;
    #pragma unroll
    for (int f=0;f<17;f++){
      float dv = dss[b][f];
      fd1 += ff[o1*17+f]*dv;
      fd2 += ff[o2*17+f]*dv;
    }
    float v = (aa*fu1+(1.f-aa)*fd1)*Wout[o1];
    if (o2v) v += (aa*fu2+(1.f-aa)*fd2)*Wout[o2];
    #pragma unroll
    for (int off=32;off>=1;off>>=1) v += __shfl_xor(v,off,64);
    if (lane==0) outp[t*512+bg] = v + biasout[0];
  }
}

// ================= weight prep (identical to R11/R12/R13) =================
__global__ void kprep(const float* __restrict__ Wih, const float* __restrict__ b_ih,
                      const float* __restrict__ b_hh, const float* __restrict__ Wt,
                      const float* __restrict__ bt_ih, const float* __restrict__ bt_hh,
                      const float* __restrict__ wp, const float* __restrict__ F1,
                      const float* __restrict__ b1, float* __restrict__ wsf)
{
  int n = blockIdx.x*256 + threadIdx.x;
  if (n < 92416){
    int jp=n&3, lane=(n>>2)&63, rest=n>>8;
    int ks=rest%19, mt=rest/19;
    int m = mt*16 + (lane&15);
    int k = ks*32 + (lane>>4)*8 + 2*jp;
    float v0 = (m<300 && k  <600)? wp[m*600+k  ] : 0.f;
    float v1 = (m<300 && k+1<600)? wp[m*600+k+1] : 0.f;
    ((unsigned*)wsf)[OFF_WBF2+n] = ((unsigned)f2usr(v1)<<16) | f2usr(v0);
    return;
  }
  n -= 92416;
  if (n < 63232){
    int jp=n&3, lane=(n>>2)&63, rest=n>>8;
    int ks=rest%19, nt=rest/19;
    int col = nt*16 + (lane&15);
    int k = ks*32 + (lane>>4)*8 + 2*jp;
    float v0=0.f, v1=0.f;
    if (col<200){
      v0 = (k  <600)? F1[k*200+col]     : (k  ==600? b1[col] : 0.f);
      v1 = (k+1<600)? F1[(k+1)*200+col] : (k+1==600? b1[col] : 0.f);
    }
    ((unsigned*)wsf)[OFF_F1S+n] = ((unsigned)f2usr(v1)<<16) | f2usr(v0);
    return;
  }
  n -= 63232;
  if (n < 108000){
    int k=n/10800, r=n%10800, h=r/36, s=r%36;
    float v;
    if (s<33){
      int i=s/3, g=s%3;
      int G = h + (g==0?0:(g==1?600:900));
      v = Wih[(k*1200+G)*11 + i];
    } else {
      int g=s-33;
      int G = h + (g==0?0:(g==1?600:900));
      v = b_ih[k*1200+G] + b_hh[k*1200+G];
    }
    wsf[OFF_WIHP2+n] = v; return;
  }
  n -= 108000;
  if (n < 900){
    int h=n%300, g=n/300;
    int G = h + (g==0?0:(g==1?600:900));
    wsf[OFF_BTP+n] = bt_ih[G]+bt_hh[G]; return;
  }
  n -= 900;
  if (n < 3600){
    int h=n%300; int q=n/300; int g=q%3, e=q/3;
    int G = h + (g==0?0:(g==1?600:900));
    wsf[OFF_WTP+n] = Wt[G*4+e]; return;
  }
}

__global__ void kprep2(const float* __restrict__ DisM, float* __restrict__ wsf){
  if (threadIdx.x==0 && blockIdx.x==0){
    float m = DisM[0];
    for (int k=1;k<10;k++) m = fmaxf(m, DisM[k]);
    float e[10]; float s=0.f;
    for (int k=0;k<10;k++){ e[k]=__expf(DisM[k]-m); s+=e[k]; }
    float inv=1.0f/s; float sw=0.f;
    for (int k=0;k<10;k++){ float v=e[k]*inv; wsf[OFF_WA+k]=v; sw+=v; }
    wsf[OFF_SWA]=sw;
  }
}

extern "C" void kernel_launch(void* const* d_in, const int* in_sizes, int n_in,
                              void* d_out, int out_size, void* d_ws, size_t ws_size,
                              hipStream_t stream)
{
  const float* li     = (const float*)d_in[0];
  const float* labels = (const float*)d_in[1];
  const float* exs    = (const float*)d_in[2];
  const float* DisM   = (const float*)d_in[3];
  const float* AngleM = (const float*)d_in[4];
  const float* Wih    = (const float*)d_in[5];
  const float* b_ih   = (const float*)d_in[6];
  const float* b_hh   = (const float*)d_in[7];
  const float* Wt     = (const float*)d_in[8];
  const float* bt_ih  = (const float*)d_in[9];
  const float* bt_hh  = (const float*)d_in[10];
  const float* wp     = (const float*)d_in[11];
  const float* bp     = (const float*)d_in[12];
  const float* F1     = (const float*)d_in[13];
  const float* b1     = (const float*)d_in[14];
  const float* F2     = (const float*)d_in[15];
  const float* b2     = (const float*)d_in[16];
  const float* ff     = (const float*)d_in[17];
  const float* bff    = (const float*)d_in[18];
  const float* fuse1  = (const float*)d_in[19];
  const float* biasf  = (const float*)d_in[20];
  const float* Wout   = (const float*)d_in[21];
  const float* biasout= (const float*)d_in[22];
  const float* a      = (const float*)d_in[23];
  float* wsf = (float*)d_ws;
  float* outp = (float*)d_out;
  unsigned* con1u = (unsigned*)((char*)d_ws + CON1_BYTE);
  u16* cong = (u16*)((char*)d_ws + CONG_BYTE);

  if (ws_size < WS_MIN_BYTES) return;

  kprep<<<dim3(1048), dim3(256), 0, stream>>>(Wih,b_ih,b_hh,Wt,bt_ih,bt_hh,wp,F1,b1,wsf);
  kprep2<<<dim3(1), dim3(64), 0, stream>>>(DisM, wsf);
  if (ws_size >= WS_SPLIT_BYTES){
    kern_cells<<<dim3(10,32,8), dim3(320), 0, stream>>>(li, wsf, cong);
    kern_main_split<<<dim3(256,32), NTHR, 0, stream>>>(li, exs, AngleM, bp, F2, b2,
                                                       wsf, con1u, wsf + OFF_SM, cong);
  } else {
    kern_main_mono<<<dim3(256,32), NTHR, 0, stream>>>(li, exs, AngleM, bp, F2, b2,
                                                      wsf, con1u, wsf + OFF_SM);
  }
  kern_final<<<dim3(128,32), NTHR, 0, stream>>>(li, labels, ff, bff, fuse1, biasf,
                                                Wout, biasout, a, wsf, con1u, outp);
}

// Round 15
// 567.901 us; speedup vs baseline: 1.4308x; 1.1221x over previous
//
#include <hip/hip_runtime.h>
#include <hip/hip_bf16.h>

// GCLSTM: B=512, T=32, H=300, K=10. f32 in/out.
// R15 = R14 with TB 2->3 (one variable): 30 valid rows of the 32-row MFMA
// N-tile (94% vs 62.5%), blocks/t 256->171 (-33% MFMA issue + barriers).
// con1u re-laid out direct-bg [(t*512+bg)*10+k]*150 (matches cong layout);
// junk rows 30-31 not zeroed (garbage lands only in discarded D entries).
// kern_cells / kern_final / kprep otherwise frozen from R14.
// ws >= 198.3MB proven by R12 (split path ran).

#define TB 3
#define NBT 171           // ceil(512/3) blocks in b
#define NR 32             // cct rows (MFMA N)
#define NTHR 640          // 10 waves
#define NW 10
#define KP 616
#define TBF 4             // kern_final b-tile

// ws layout (u32 slots) — identical to R11..R14
#define OFF_SM    0         // softmax [32][10][512] f32          163840
#define OFF_WBF2  163840    // wp A-frags [mt19][ks19][lane64][4]  92416
#define OFF_F1S   256256    // F1 B-frags [nt13][ks19][lane64][4]  63232
#define OFF_WIHP2 319488    // cells [k10][h300][36] f32 (33-35=bias) 108000
#define OFF_BTP   427488    // g*300+h f32                           900
#define OFF_WTP   428388    // (e*3+g)*300+h f32                    3600
#define OFF_WA    431988    // softmax(DisM) f32                      10
#define OFF_SWA   431998    // sum(wA) f32                             1
#define BASE_U32  432000
#define CON1_BYTE ((size_t)BASE_U32 * 4)                  // 1,728,000
#define WS_MIN_BYTES (CON1_BYTE + (size_t)98304000)       // 100,032,000
#define CONG_BYTE  WS_MIN_BYTES                           // con_g right after con1u
#define WS_SPLIT_BYTES (CONG_BYTE + (size_t)98304000)     // 198,336,000 (proven fits)

typedef __attribute__((ext_vector_type(8))) short s16x8;
typedef __attribute__((ext_vector_type(4))) float f32x4;
typedef unsigned short u16;

__device__ __forceinline__ float rcpf(float x){ return __builtin_amdgcn_rcpf(x); }
__device__ __forceinline__ float sigf(float x){ return rcpf(1.0f+__expf(-x)); }
__device__ __forceinline__ float tanhf_(float x){ return 1.0f - 2.0f*rcpf(__expf(2.0f*x)+1.0f); }
__device__ __forceinline__ float bfu(u16 u){ return __uint_as_float(((unsigned)u)<<16); }
__device__ __forceinline__ u16 f2us(float f){ return (u16)(__float_as_uint(f)>>16); }
__device__ __forceinline__ u16 f2usr(float f){   // RNE bf16
  __hip_bfloat16 h = __float2bfloat16(f);
  return *(u16*)&h;
}

// ===== split path: cells once per (t,b,k,h); block=(k,t,b64), thread=h =====
__global__ __launch_bounds__(320,4) void kern_cells(
    const float* __restrict__ li, const float* wsf, u16* __restrict__ cong)
{
  __shared__ __align__(16) float xs[64][12];   // 3 KB; col 11 = pad
  const int tid=threadIdx.x, k=blockIdx.x, t=blockIdx.y, bh=blockIdx.z;
  const int bbase = bh*64;
  for (int p=tid; p<64*11; p+=320){
    int b=p/11, i=p%11;
    xs[b][i] = li[(((size_t)(bbase+b)*32+t)*28+i)*10+k];
  }
  __syncthreads();
  const int h = tid;
  if (h < 300){
    const float4* Wp = (const float4*)(wsf + OFF_WIHP2 + (size_t)(k*300+h)*36);
    float f[36];
    #pragma unroll
    for (int q=0;q<9;q++){
      float4 v = Wp[q];
      f[4*q+0]=v.x; f[4*q+1]=v.y; f[4*q+2]=v.z; f[4*q+3]=v.w;
    }
    // cong layout: [(t*512+bg)*10+k]*300 + h  (u16)
    u16* out = cong + ((size_t)t*5120 + (size_t)bbase*10 + k)*300 + h;
    #pragma unroll 4
    for (int b=0;b<64;b++){
      float ai=f[33], ag=f[34], ao=f[35];
      #pragma unroll
      for (int i=0;i<11;i++){
        float xv = xs[b][i];   // wave-uniform address -> LDS broadcast
        ai += f[3*i+0]*xv; ag += f[3*i+1]*xv; ao += f[3*i+2]*xv;
      }
      float hv = sigf(ao) * tanhf_( sigf(ai) * tanhf_(ag) );
      out[(size_t)b*3000] = f2usr(hv);
    }
  }
}

// ============ kern_main body shared by both paths via template ============
template<int SPLIT>
__device__ __forceinline__ void kern_main_body(
    const float* __restrict__ li, const float* __restrict__ exs,
    const float* __restrict__ AngleM, const float* __restrict__ bp,
    const float* __restrict__ F2, const float* __restrict__ b2,
    const float* wsf, unsigned* __restrict__ con1u, float* smg,
    const u16* __restrict__ cong)
{
  __shared__ __align__(16) u16 cct[NR][KP];   // 39,424 B
  __shared__ float xs[2][TB][11][10];
  __shared__ float xse[TB][2][10];
  __shared__ float exss[TB][4];
  __shared__ float wdP[NW][NR];
  __shared__ float wdL[NR];
  const int tid = threadIdx.x;
  const int t = blockIdx.y, bt = blockIdx.x, b0 = bt*TB;
  const int w = tid>>6, lane = tid&63, lo = lane&15, qd = lane>>4;

  // ---- P0 ----
  if (!SPLIT){
    for (int p=tid; p<2*TB*110; p+=NTHR){
      int half=p/(110*TB), r=p%(110*TB), b=r/110, q=r%110, i=q/10, k=q%10;
      int tp = half ? (t>0? t-1 : 0) : t;
      int bg = b0+b; if (bg>511) bg=511;
      xs[half][b][i][k] = li[(((bg)*32+tp)*28+i)*10+k];
    }
  }
  for (int p=tid;p<TB*20;p+=NTHR){
    int b=p/20, r=p%20, rr=r/10, k=r%10;
    int bg = b0+b; if (bg>511) bg=511;
    xse[b][rr][k] = li[((bg*32+t)*28 + (rr?10:8))*10 + k];
  }
  for (int p=tid;p<TB*4;p+=NTHR){
    int b=p/4, e=p%4;
    int bg = b0+b; if (bg>511) bg=511;
    exss[b][e] = exs[(bg*32+t)*4+e];
  }
  for (int p=tid; p<30*4; p+=NTHR){   // rows 0..29, K-pad cols 600-607
    int n=p/4, c=p%4;
    ((unsigned*)&cct[n][600])[c] = 0u;
  }
  __syncthreads();

  // ---- P1: con(t) -> cols 0-299, con(t-1) -> cols 300-599 ----
  const int nh = (t==0)?1:2;
  if (SPLIT){
    for (int p=tid; p<nh*TB*1500; p+=NTHR){
      int half=p/(TB*1500), r=p%(TB*1500), n=r/150, op=r%150;
      int tp = half? t-1 : t;
      int bg = b0 + n/10; if (bg>511) bg=511;
      unsigned v = ((const unsigned*)cong)[ ((size_t)(tp*512+bg)*10 + n%10)*150 + op ];
      *(unsigned*)&cct[n][300*half + 2*op] = v;
    }
  } else {
    for (int pt=tid; pt<3000; pt+=NTHR){
      int k=pt/300, h=pt%300;
      const float4* Wp = (const float4*)(wsf + OFF_WIHP2 + (size_t)(k*300+h)*36);
      float f[36];
      #pragma unroll
      for (int q=0;q<9;q++){
        float4 v = Wp[q];
        f[4*q+0]=v.x; f[4*q+1]=v.y; f[4*q+2]=v.z; f[4*q+3]=v.w;
      }
      for (int half=0; half<nh; half++){
        #pragma unroll
        for (int b=0;b<TB;b++){
          float ai=f[33], ag=f[34], ao=f[35];
          #pragma unroll
          for (int i=0;i<11;i++){
            float xv = xs[half][b][i][k];
            ai += f[3*i+0]*xv; ag += f[3*i+1]*xv; ao += f[3*i+2]*xv;
          }
          float hv = sigf(ao) * tanhf_( sigf(ai) * tanhf_(ag) );
          cct[b*10+k][h+300*half] = f2usr(hv);
        }
      }
    }
  }
  __syncthreads();

  // ---- P2: wp-MFMA  D[o 304][n 32]; 2 Mtiles/wave, 2 Ntiles ----
  f32x4 acc[2][2];
  #pragma unroll
  for (int i=0;i<2;i++)
    #pragma unroll
    for (int nt=0;nt<2;nt++) acc[i][nt] = (f32x4){0.f,0.f,0.f,0.f};
  if (t>0){
    const u16* wbfA = (const u16*)((const unsigned*)wsf + OFF_WBF2);
    for (int ks=0; ks<19; ks++){
      const int kb = ks*32 + qd*8;
      s16x8 Bv[2];
      #pragma unroll
      for (int nt=0;nt<2;nt++)
        Bv[nt] = *(const s16x8*)&cct[nt*16+lo][kb];
      #pragma unroll
      for (int i=0;i<2;i++){
        int mt = w*2+i;
        if (mt<19){
          s16x8 Av = *(const s16x8*)(wbfA + ((size_t)(mt*19+ks)*64 + lane)*8);
          #pragma unroll
          for (int nt=0;nt<2;nt++)
            acc[i][nt] = __builtin_amdgcn_mfma_f32_16x16x32_bf16(Av, Bv[nt], acc[i][nt], 0,0,0);
        }
      }
    }
  }
  __syncthreads();

  // ---- P2b (t>0): epilogue transpose ----
  if (t>0){
    #pragma unroll
    for (int i=0;i<2;i++){
      int mt = w*2+i;
      if (mt<19 && (mt<18 || qd<3)){
        int ob = mt*16 + qd*4;
        float p0=bp[ob], p1=bp[ob+1], p2=bp[ob+2], p3=bp[ob+3];
        #pragma unroll
        for (int nt=0;nt<2;nt++){
          int n = nt*16+lo;
          float v0=acc[i][nt][0]+p0, v1=acc[i][nt][1]+p1,
                v2=acc[i][nt][2]+p2, v3=acc[i][nt][3]+p3;
          unsigned w0 = ((unsigned)f2us(v1>0.f?v1:0.f)<<16) | f2us(v0>0.f?v0:0.f);
          unsigned w1 = ((unsigned)f2us(v3>0.f?v3:0.f)<<16) | f2us(v2>0.f?v2:0.f);
          *(unsigned*)&cct[n][ob]   = w0;
          *(unsigned*)&cct[n][ob+2] = w1;
        }
      }
    }
  }
  // ---- P3: htarget -> hcat cols [300,600); col 600 = 1.0 ----
  for (int p=tid; p<TB*300; p+=NTHR){
    int b=p/300, o=p%300;
    float ai=0.f, ag=0.f, ao=0.f;
    #pragma unroll
    for (int e=0;e<4;e++){
      float xv = exss[b][e];
      ai += wsf[OFF_WTP+(e*3+0)*300+o]*xv;
      ag += wsf[OFF_WTP+(e*3+1)*300+o]*xv;
      ao += wsf[OFF_WTP+(e*3+2)*300+o]*xv;
    }
    ai += wsf[OFF_BTP+o]; ag += wsf[OFF_BTP+300+o]; ao += wsf[OFF_BTP+600+o];
    u16 u = f2usr( sigf(ao)*tanhf_(sigf(ai)*tanhf_(ag)) );
    #pragma unroll
    for (int k=0;k<10;k++) cct[b*10+k][300+o] = u;
  }
  for (int p=tid; p<30*4; p+=NTHR){
    int n=p/4, c=p%4;
    ((unsigned*)&cct[n][600])[c] = (c==0)? 0x00003f80u : 0u;
  }
  __syncthreads();

  // ---- P5: store con1 tile, direct-bg layout [(t*512+bg)*10+k]*150+op ----
  for (int p=tid; p<TB*1500; p+=NTHR){
    int n=p/150, op=p%150;
    int bg = b0 + n/10;
    if (bg < 512)
      con1u[ ((size_t)(t*512+bg)*10 + n%10)*150 + op ] = *(const unsigned*)&cct[n][2*op];
  }

  // ---- P4: F1-MFMA  fc1[n 32][j 208]; 2 Mtiles, nt in {w, w+10} ----
  f32x4 acc2[2][2];
  #pragma unroll
  for (int mt=0;mt<2;mt++)
    #pragma unroll
    for (int j=0;j<2;j++) acc2[mt][j] = (f32x4){0.f,0.f,0.f,0.f};
  {
    const u16* f1s = (const u16*)((const unsigned*)wsf + OFF_F1S);
    for (int ks=0; ks<19; ks++){
      const int kb = ks*32 + qd*8;
      s16x8 Am[2];
      #pragma unroll
      for (int mt=0;mt<2;mt++)
        Am[mt] = *(const s16x8*)&cct[mt*16+lo][kb];
      #pragma unroll
      for (int j=0;j<2;j++){
        int nt = w + j*NW;
        if (nt<13){
          s16x8 Bf = *(const s16x8*)(f1s + ((size_t)(nt*19+ks)*64 + lane)*8);
          #pragma unroll
          for (int mt=0;mt<2;mt++)
            acc2[mt][j] = __builtin_amdgcn_mfma_f32_16x16x32_bf16(Am[mt], Bf, acc2[mt][j], 0,0,0);
        }
      }
    }
  }
  {
    float f2c[2];
    #pragma unroll
    for (int j=0;j<2;j++){
      int nt = w + j*NW;
      int jj = nt*16+lo;
      f2c[j] = (nt<13 && jj<200)? F2[jj] : 0.f;
    }
    #pragma unroll
    for (int mt=0;mt<2;mt++)
      #pragma unroll
      for (int r=0;r<4;r++){
        float s = 0.f;
        #pragma unroll
        for (int j=0;j<2;j++){
          float v = acc2[mt][j][r];
          s += (v>0.f? v:0.f) * f2c[j];
        }
        s += __shfl_xor(s,1,64); s += __shfl_xor(s,2,64);
        s += __shfl_xor(s,4,64); s += __shfl_xor(s,8,64);
        if (lo==0) wdP[w][mt*16+qd*4+r] = s;
      }
  }
  __syncthreads();
  if (tid<TB*10){
    int n=tid, b=n/10, k=n%10;
    float v = 0.f;
    #pragma unroll
    for (int ww=0;ww<NW;ww++) v += wdP[ww][n];
    float ang = fabsf(xse[b][1][k]-AngleM[k]) * (1.0f/360.0f);
    v += xse[b][0][k]*F2[200] + ang*F2[201] + b2[0];
    wdL[n] = v>0.f? v : 0.f;
  }
  __syncthreads();
  if (tid<TB && b0+tid < 512){
    int b=tid;
    float m = wdL[b*10];
    #pragma unroll
    for (int k=1;k<10;k++) m = fmaxf(m, wdL[b*10+k]);
    float e[10]; float s=0.f;
    #pragma unroll
    for (int k=0;k<10;k++){ e[k]=__expf(wdL[b*10+k]-m); s+=e[k]; }
    float inv = rcpf(s);
    #pragma unroll
    for (int k=0;k<10;k++) smg[t*5120 + k*512 + b0+b] = e[k]*inv;
  }
}

__global__ __launch_bounds__(NTHR,2) void kern_main_mono(
    const float* __restrict__ li, const float* __restrict__ exs,
    const float* __restrict__ AngleM, const float* __restrict__ bp,
    const float* __restrict__ F2, const float* __restrict__ b2,
    const float* wsf, unsigned* __restrict__ con1u, float* smg)
{
  kern_main_body<0>(li,exs,AngleM,bp,F2,b2,wsf,con1u,smg,(const u16*)nullptr);
}

__global__ __launch_bounds__(NTHR,2) void kern_main_split(
    const float* __restrict__ li, const float* __restrict__ exs,
    const float* __restrict__ AngleM, const float* __restrict__ bp,
    const float* __restrict__ F2, const float* __restrict__ b2,
    const float* wsf, unsigned* __restrict__ con1u, float* smg,
    const u16* __restrict__ cong)
{
  kern_main_body<1>(li,exs,AngleM,bp,F2,b2,wsf,con1u,smg,cong);
}

// ====== final: gather scramble, fuse, preds (+ labels copy fused); TBF=4 ======
__global__ __launch_bounds__(NTHR,3) void kern_final(
    const float* __restrict__ li, const float* __restrict__ labels,
    const float* __restrict__ ff, const float* __restrict__ bff,
    const float* __restrict__ fuse1, const float* __restrict__ biasf,
    const float* __restrict__ Wout, const float* __restrict__ biasout,
    const float* __restrict__ a, const float* wsf,
    const unsigned* __restrict__ con1u, float* __restrict__ outp)
{
  __shared__ unsigned conTu[40][152];
  __shared__ float xs17[TBF][17][10];
  __shared__ float cats[TBF][300];
  __shared__ float wa3s[TBF][10];
  __shared__ float dss[TBF][17];
  __shared__ float wAs[10];
  __shared__ float fup1[8][64], fup2[8][64];
  const int tid=threadIdx.x, t=blockIdx.y, bt=blockIdx.x, b0=bt*TBF;
  if (tid>=NTHR-TBF && tid<NTHR){
    int b = tid-(NTHR-TBF);
    outp[16384 + t*512 + b0+b] = labels[(b0+b)*32+t];
  }
  for (int p=tid;p<TBF*170;p+=NTHR){
    int b=p/170, r=p%170, f=r/10, k=r%10;
    xs17[b][f][k] = li[(((b0+b)*32+t)*28 + 11+f)*10 + k];
  }
  if (tid<10) wAs[tid] = wsf[OFF_WA+tid];
  for (int p=tid;p<6000;p+=NTHR){   // direct-bg con1u layout
    int n4=p/150, op=p%150;
    int b=n4/10, k=n4%10, bg=b0+b;
    conTu[n4][op] = con1u[ ((size_t)(t*512+bg)*10 + k)*150 + op ];
  }
  __syncthreads();
  for (int p=tid;p<TBF*10;p+=NTHR){
    int b=p/10, k=p%10;
    int g = (b0+b)*10+k;
    wa3s[b][k] = wsf[OFF_SM + t*5120 + (g>>9)*512 + (g&511)];
  }
  for (int p=tid;p<TBF*17;p+=NTHR){
    int b=p/17, f=p%17; float s=0.f;
    #pragma unroll
    for (int k=0;k<10;k++) s += xs17[b][f][k]*wAs[k];
    dss[b][f]=s;
  }
  __syncthreads();
  const u16* conT = (const u16*)conTu;
  for (int p=tid;p<TBF*300;p+=NTHR){
    int b=p/300, h=p%300;
    float s=0.f;
    #pragma unroll
    for (int k=0;k<10;k++)
      s += bfu(conT[(b*10+k)*304 + h]) * wa3s[b][k];
    cats[b][h]=s;
  }
  __syncthreads();
  const int w = tid>>6, lane = tid&63;
  const int o1 = lane;
  const bool o2v = lane<36;
  const int o2 = o2v ? (64+lane) : 99;
  if (w<8){
    int b=w>>1, half=w&1;
    float fu1 = half? 0.f : biasf[o1];
    float fu2 = half? 0.f : biasf[o2];
    const int hb = half*150;
    for (int h=hb; h<hb+150; h++){
      float cv = cats[b][h];
      fu1 += cv*fuse1[h*100+o1];
      fu2 += cv*fuse1[h*100+o2];
    }
    fup1[w][lane]=fu1; fup2[w][lane]=fu2;
  }
  __syncthreads();
  if (w<TBF){
    const int b=w, bg=b0+b;
    const float aa = a[0], swa = wsf[OFF_SWA];
    float fu1 = fup1[2*b][lane] + fup1[2*b+1][lane];
    float fu2 = fup2[2*b][lane] + fup2[2*b+1][lane];
    float fd1 = bff[o1]*swa, fd2 = bff[o2]*swa;
    #pragma unroll
    for (int f=0;f<17;f++){
      float dv = dss[b][f];
      fd1 += ff[o1*17+f]*dv;
      fd2 += ff[o2*17+f]*dv;
    }
    float v = (aa*fu1+(1.f-aa)*fd1)*Wout[o1];
    if (o2v) v += (aa*fu2+(1.f-aa)*fd2)*Wout[o2];
    #pragma unroll
    for (int off=32;off>=1;off>>=1) v += __shfl_xor(v,off,64);
    if (lane==0) outp[t*512+bg] = v + biasout[0];
  }
}

// ================= weight prep (identical to R11..R14) =================
__global__ void kprep(const float* __restrict__ Wih, const float* __restrict__ b_ih,
                      const float* __restrict__ b_hh, const float* __restrict__ Wt,
                      const float* __restrict__ bt_ih, const float* __restrict__ bt_hh,
                      const float* __restrict__ wp, const float* __restrict__ F1,
                      const float* __restrict__ b1, float* __restrict__ wsf)
{
  int n = blockIdx.x*256 + threadIdx.x;
  if (n < 92416){
    int jp=n&3, lane=(n>>2)&63, rest=n>>8;
    int ks=rest%19, mt=rest/19;
    int m = mt*16 + (lane&15);
    int k = ks*32 + (lane>>4)*8 + 2*jp;
    float v0 = (m<300 && k  <600)? wp[m*600+k  ] : 0.f;
    float v1 = (m<300 && k+1<600)? wp[m*600+k+1] : 0.f;
    ((unsigned*)wsf)[OFF_WBF2+n] = ((unsigned)f2usr(v1)<<16) | f2usr(v0);
    return;
  }
  n -= 92416;
  if (n < 63232){
    int jp=n&3, lane=(n>>2)&63, rest=n>>8;
    int ks=rest%19, nt=rest/19;
    int col = nt*16 + (lane&15);
    int k = ks*32 + (lane>>4)*8 + 2*jp;
    float v0=0.f, v1=0.f;
    if (col<200){
      v0 = (k  <600)? F1[k*200+col]     : (k  ==600? b1[col] : 0.f);
      v1 = (k+1<600)? F1[(k+1)*200+col] : (k+1==600? b1[col] : 0.f);
    }
    ((unsigned*)wsf)[OFF_F1S+n] = ((unsigned)f2usr(v1)<<16) | f2usr(v0);
    return;
  }
  n -= 63232;
  if (n < 108000){
    int k=n/10800, r=n%10800, h=r/36, s=r%36;
    float v;
    if (s<33){
      int i=s/3, g=s%3;
      int G = h + (g==0?0:(g==1?600:900));
      v = Wih[(k*1200+G)*11 + i];
    } else {
      int g=s-33;
      int G = h + (g==0?0:(g==1?600:900));
      v = b_ih[k*1200+G] + b_hh[k*1200+G];
    }
    wsf[OFF_WIHP2+n] = v; return;
  }
  n -= 108000;
  if (n < 900){
    int h=n%300, g=n/300;
    int G = h + (g==0?0:(g==1?600:900));
    wsf[OFF_BTP+n] = bt_ih[G]+bt_hh[G]; return;
  }
  n -= 900;
  if (n < 3600){
    int h=n%300; int q=n/300; int g=q%3, e=q/3;
    int G = h + (g==0?0:(g==1?600:900));
    wsf[OFF_WTP+n] = Wt[G*4+e]; return;
  }
}

__global__ void kprep2(const float* __restrict__ DisM, float* __restrict__ wsf){
  if (threadIdx.x==0 && blockIdx.x==0){
    float m = DisM[0];
    for (int k=1;k<10;k++) m = fmaxf(m, DisM[k]);
    float e[10]; float s=0.f;
    for (int k=0;k<10;k++){ e[k]=__expf(DisM[k]-m); s+=e[k]; }
    float inv=1.0f/s; float sw=0.f;
    for (int k=0;k<10;k++){ float v=e[k]*inv; wsf[OFF_WA+k]=v; sw+=v; }
    wsf[OFF_SWA]=sw;
  }
}

extern "C" void kernel_launch(void* const* d_in, const int* in_sizes, int n_in,
                              void* d_out, int out_size, void* d_ws, size_t ws_size,
                              hipStream_t stream)
{
  const float* li     = (const float*)d_in[0];
  const float* labels = (const float*)d_in[1];
  const float* exs    = (const float*)d_in[2];
  const float* DisM   = (const float*)d_in[3];
  const float* AngleM = (const float*)d_in[4];
  const float* Wih    = (const float*)d_in[5];
  const float* b_ih   = (const float*)d_in[6];
  const float* b_hh   = (const float*)d_in[7];
  const float* Wt     = (const float*)d_in[8];
  const float* bt_ih  = (const float*)d_in[9];
  const float* bt_hh  = (const float*)d_in[10];
  const float* wp     = (const float*)d_in[11];
  const float* bp     = (const float*)d_in[12];
  const float* F1     = (const float*)d_in[13];
  const float* b1     = (const float*)d_in[14];
  const float* F2     = (const float*)d_in[15];
  const float* b2     = (const float*)d_in[16];
  const float* ff     = (const float*)d_in[17];
  const float* bff    = (const float*)d_in[18];
  const float* fuse1  = (const float*)d_in[19];
  const float* biasf  = (const float*)d_in[20];
  const float* Wout   = (const float*)d_in[21];
  const float* biasout= (const float*)d_in[22];
  const float* a      = (const float*)d_in[23];
  float* wsf = (float*)d_ws;
  float* outp = (float*)d_out;
  unsigned* con1u = (unsigned*)((char*)d_ws + CON1_BYTE);
  u16* cong = (u16*)((char*)d_ws + CONG_BYTE);

  if (ws_size < WS_MIN_BYTES) return;

  kprep<<<dim3(1048), dim3(256), 0, stream>>>(Wih,b_ih,b_hh,Wt,bt_ih,bt_hh,wp,F1,b1,wsf);
  kprep2<<<dim3(1), dim3(64), 0, stream>>>(DisM, wsf);
  if (ws_size >= WS_SPLIT_BYTES){
    kern_cells<<<dim3(10,32,8), dim3(320), 0, stream>>>(li, wsf, cong);
    kern_main_split<<<dim3(NBT,32), NTHR, 0, stream>>>(li, exs, AngleM, bp, F2, b2,
                                                       wsf, con1u, wsf + OFF_SM, cong);
  } else {
    kern_main_mono<<<dim3(NBT,32), NTHR, 0, stream>>>(li, exs, AngleM, bp, F2, b2,
                                                      wsf, con1u, wsf + OFF_SM);
  }
  kern_final<<<dim3(128,32), NTHR, 0, stream>>>(li, labels, ff, bff, fuse1, biasf,
                                                Wout, biasout, a, wsf, con1u, outp);
}

// Round 16
// 529.674 us; speedup vs baseline: 1.5341x; 1.0722x over previous
//
#include <hip/hip_runtime.h>
#include <hip/hip_bf16.h>

// GCLSTM: B=512, T=32, H=300, K=10. f32 in/out.
// R16 = R15 with kern_cells rewritten as MFMA: wave<->Mtile of 16 tb-rows,
// G[tb 16][h 16] = X[16][12+pad] @ Wg[12][16] per gate (16x16x32, K zero-pad,
// half-table B-frags: kk>=16 rows are zero so only qd<2 lanes stored);
// transcendental epilogue runs on ALL 64 lanes (4 evals/lane) — fixes R8's
// quarter-utilization mistake. Mono path deleted (ws >= 198,336,000 proven
// by R12; new footprint 198,195,840 <= that). kern_main_split / kern_final
// frozen from R15 (only ws offsets shifted).

#define TB 3
#define NBT 171           // ceil(512/3) blocks in b
#define NR 32             // cct rows (MFMA N)
#define NTHR 640          // 10 waves
#define NW 10
#define KP 616
#define TBF 4             // kern_final b-tile

// ws layout (u32 slots)
#define OFF_SM    0         // softmax [32][10][512] f32          163840
#define OFF_WBF2  163840    // wp A-frags [mt19][ks19][lane64][4]  92416
#define OFF_F1S   256256    // F1 B-frags [nt13][ks19][lane64][4]  63232
#define OFF_WCELL 319488    // cells B-frags [k10][ht19][g3][l32][4] 72960
#define OFF_BTP   392448    // g*300+h f32                           900
#define OFF_WTP   393348    // (e*3+g)*300+h f32                    3600
#define OFF_WA    396948    // softmax(DisM) f32                      10
#define OFF_SWA   396958    // sum(wA) f32                             1
#define BASE_U32  396960
#define CON1_BYTE ((size_t)BASE_U32 * 4)                  // 1,587,840
#define CONG_BYTE (CON1_BYTE + (size_t)98304000)          // 99,891,840
#define WS_NEED_BYTES (CONG_BYTE + (size_t)98304000)      // 198,195,840 (< proven 198,336,000)

typedef __attribute__((ext_vector_type(8))) short s16x8;
typedef __attribute__((ext_vector_type(4))) float f32x4;
typedef unsigned short u16;

__device__ __forceinline__ float rcpf(float x){ return __builtin_amdgcn_rcpf(x); }
__device__ __forceinline__ float sigf(float x){ return rcpf(1.0f+__expf(-x)); }
__device__ __forceinline__ float tanhf_(float x){ return 1.0f - 2.0f*rcpf(__expf(2.0f*x)+1.0f); }
__device__ __forceinline__ float bfu(u16 u){ return __uint_as_float(((unsigned)u)<<16); }
__device__ __forceinline__ u16 f2us(float f){ return (u16)(__float_as_uint(f)>>16); }
__device__ __forceinline__ u16 f2usr(float f){   // RNE bf16
  __hip_bfloat16 h = __float2bfloat16(f);
  return *(u16*)&h;
}

// ===== cells-MFMA: block=(k, 64 tb-rows); 4 waves = 4 Mtiles =====
__global__ __launch_bounds__(256,4) void kern_cells(
    const float* __restrict__ li, const float* wsf, u16* __restrict__ cong)
{
  __shared__ __align__(16) float xs[64][12];   // 3 KB; col 11 = 1.0 bias row
  const int tid=threadIdx.x, k=blockIdx.x;
  const int tbase = blockIdx.y*64;             // 64 | 512 -> single t per block
  const int t = tbase>>9, bg0 = tbase&511;
  for (int p=tid; p<64*11; p+=256){
    int r=p/11, i=p%11;
    xs[r][i] = li[(((size_t)(bg0+r)*32+t)*28+i)*10+k];
  }
  if (tid<64) xs[tid][11] = 1.0f;
  __syncthreads();
  const int w = tid>>6, lane = tid&63, lo=lane&15, qd=lane>>4;
  // A-frag (verified 16x16x32 layout): A[m=lo][kk=qd*8+j]; kk>=12 -> 0
  short av[8];
  #pragma unroll
  for (int j=0;j<8;j++){
    int kk = qd*8+j;
    float v = (kk<12)? xs[w*16+lo][kk] : 0.f;
    av[j] = (short)f2usr(v);
  }
  s16x8 Ax = (s16x8){av[0],av[1],av[2],av[3],av[4],av[5],av[6],av[7]};
  const unsigned* wc = (const unsigned*)wsf + OFF_WCELL;
  const s16x8 Z = (s16x8){0,0,0,0,0,0,0,0};
  for (int ht=0; ht<19; ht++){
    s16x8 Bi=Z, Bg=Z, Bo=Z;
    if (qd<2){   // B[kk=qd*8+j][col=lo]; kk>=16 rows are all zero (not stored)
      const unsigned* bb = wc + (((k*19+ht)*3)*32 + qd*16+lo)*4;
      Bi = *(const s16x8*)(bb);
      Bg = *(const s16x8*)(bb + 32*4);
      Bo = *(const s16x8*)(bb + 64*4);
    }
    f32x4 gi={0.f,0.f,0.f,0.f}, gg={0.f,0.f,0.f,0.f}, go={0.f,0.f,0.f,0.f};
    gi = __builtin_amdgcn_mfma_f32_16x16x32_bf16(Ax, Bi, gi, 0,0,0);
    gg = __builtin_amdgcn_mfma_f32_16x16x32_bf16(Ax, Bg, gg, 0,0,0);
    go = __builtin_amdgcn_mfma_f32_16x16x32_bf16(Ax, Bo, go, 0,0,0);
    int h = ht*16+lo;
    if (h<300){   // D[m=qd*4+r][n=lo]: m->tb row, n->h; 4 evals/lane, all lanes
      #pragma unroll
      for (int r=0;r<4;r++){
        float hv = sigf(go[r]) * tanhf_( sigf(gi[r]) * tanhf_(gg[r]) );
        int tb = tbase + w*16 + qd*4 + r;
        cong[((size_t)tb*10+k)*300 + h] = f2usr(hv);
      }
    }
  }
}

// ============ kern_main (split only; mono deleted) ============
__global__ __launch_bounds__(NTHR,2) void kern_main_split(
    const float* __restrict__ li, const float* __restrict__ exs,
    const float* __restrict__ AngleM, const float* __restrict__ bp,
    const float* __restrict__ F2, const float* __restrict__ b2,
    const float* wsf, unsigned* __restrict__ con1u, float* smg,
    const u16* __restrict__ cong)
{
  __shared__ __align__(16) u16 cct[NR][KP];   // 39,424 B
  __shared__ float xse[TB][2][10];
  __shared__ float exss[TB][4];
  __shared__ float wdP[NW][NR];
  __shared__ float wdL[NR];
  const int tid = threadIdx.x;
  const int t = blockIdx.y, bt = blockIdx.x, b0 = bt*TB;
  const int w = tid>>6, lane = tid&63, lo = lane&15, qd = lane>>4;

  // ---- P0 ----
  for (int p=tid;p<TB*20;p+=NTHR){
    int b=p/20, r=p%20, rr=r/10, k=r%10;
    int bg = b0+b; if (bg>511) bg=511;
    xse[b][rr][k] = li[((bg*32+t)*28 + (rr?10:8))*10 + k];
  }
  for (int p=tid;p<TB*4;p+=NTHR){
    int b=p/4, e=p%4;
    int bg = b0+b; if (bg>511) bg=511;
    exss[b][e] = exs[(bg*32+t)*4+e];
  }
  for (int p=tid; p<30*4; p+=NTHR){   // rows 0..29, K-pad cols 600-607
    int n=p/4, c=p%4;
    ((unsigned*)&cct[n][600])[c] = 0u;
  }
  __syncthreads();

  // ---- P1: con(t) -> cols 0-299, con(t-1) -> cols 300-599 ----
  const int nh = (t==0)?1:2;
  for (int p=tid; p<nh*TB*1500; p+=NTHR){
    int half=p/(TB*1500), r=p%(TB*1500), n=r/150, op=r%150;
    int tp = half? t-1 : t;
    int bg = b0 + n/10; if (bg>511) bg=511;
    unsigned v = ((const unsigned*)cong)[ ((size_t)(tp*512+bg)*10 + n%10)*150 + op ];
    *(unsigned*)&cct[n][300*half + 2*op] = v;
  }
  __syncthreads();

  // ---- P2: wp-MFMA  D[o 304][n 32]; 2 Mtiles/wave, 2 Ntiles ----
  f32x4 acc[2][2];
  #pragma unroll
  for (int i=0;i<2;i++)
    #pragma unroll
    for (int nt=0;nt<2;nt++) acc[i][nt] = (f32x4){0.f,0.f,0.f,0.f};
  if (t>0){
    const u16* wbfA = (const u16*)((const unsigned*)wsf + OFF_WBF2);
    for (int ks=0; ks<19; ks++){
      const int kb = ks*32 + qd*8;
      s16x8 Bv[2];
      #pragma unroll
      for (int nt=0;nt<2;nt++)
        Bv[nt] = *(const s16x8*)&cct[nt*16+lo][kb];
      #pragma unroll
      for (int i=0;i<2;i++){
        int mt = w*2+i;
        if (mt<19){
          s16x8 Av = *(const s16x8*)(wbfA + ((size_t)(mt*19+ks)*64 + lane)*8);
          #pragma unroll
          for (int nt=0;nt<2;nt++)
            acc[i][nt] = __builtin_amdgcn_mfma_f32_16x16x32_bf16(Av, Bv[nt], acc[i][nt], 0,0,0);
        }
      }
    }
  }
  __syncthreads();

  // ---- P2b (t>0): epilogue transpose ----
  if (t>0){
    #pragma unroll
    for (int i=0;i<2;i++){
      int mt = w*2+i;
      if (mt<19 && (mt<18 || qd<3)){
        int ob = mt*16 + qd*4;
        float p0=bp[ob], p1=bp[ob+1], p2=bp[ob+2], p3=bp[ob+3];
        #pragma unroll
        for (int nt=0;nt<2;nt++){
          int n = nt*16+lo;
          float v0=acc[i][nt][0]+p0, v1=acc[i][nt][1]+p1,
                v2=acc[i][nt][2]+p2, v3=acc[i][nt][3]+p3;
          unsigned w0 = ((unsigned)f2us(v1>0.f?v1:0.f)<<16) | f2us(v0>0.f?v0:0.f);
          unsigned w1 = ((unsigned)f2us(v3>0.f?v3:0.f)<<16) | f2us(v2>0.f?v2:0.f);
          *(unsigned*)&cct[n][ob]   = w0;
          *(unsigned*)&cct[n][ob+2] = w1;
        }
      }
    }
  }
  // ---- P3: htarget -> hcat cols [300,600); col 600 = 1.0 ----
  for (int p=tid; p<TB*300; p+=NTHR){
    int b=p/300, o=p%300;
    float ai=0.f, ag=0.f, ao=0.f;
    #pragma unroll
    for (int e=0;e<4;e++){
      float xv = exss[b][e];
      ai += wsf[OFF_WTP+(e*3+0)*300+o]*xv;
      ag += wsf[OFF_WTP+(e*3+1)*300+o]*xv;
      ao += wsf[OFF_WTP+(e*3+2)*300+o]*xv;
    }
    ai += wsf[OFF_BTP+o]; ag += wsf[OFF_BTP+300+o]; ao += wsf[OFF_BTP+600+o];
    u16 u = f2usr( sigf(ao)*tanhf_(sigf(ai)*tanhf_(ag)) );
    #pragma unroll
    for (int k=0;k<10;k++) cct[b*10+k][300+o] = u;
  }
  for (int p=tid; p<30*4; p+=NTHR){
    int n=p/4, c=p%4;
    ((unsigned*)&cct[n][600])[c] = (c==0)? 0x00003f80u : 0u;
  }
  __syncthreads();

  // ---- P5: store con1 tile, direct-bg layout [(t*512+bg)*10+k]*150+op ----
  for (int p=tid; p<TB*1500; p+=NTHR){
    int n=p/150, op=p%150;
    int bg = b0 + n/10;
    if (bg < 512)
      con1u[ ((size_t)(t*512+bg)*10 + n%10)*150 + op ] = *(const unsigned*)&cct[n][2*op];
  }

  // ---- P4: F1-MFMA  fc1[n 32][j 208]; 2 Mtiles, nt in {w, w+10} ----
  f32x4 acc2[2][2];
  #pragma unroll
  for (int mt=0;mt<2;mt++)
    #pragma unroll
    for (int j=0;j<2;j++) acc2[mt][j] = (f32x4){0.f,0.f,0.f,0.f};
  {
    const u16* f1s = (const u16*)((const unsigned*)wsf + OFF_F1S);
    for (int ks=0; ks<19; ks++){
      const int kb = ks*32 + qd*8;
      s16x8 Am[2];
      #pragma unroll
      for (int mt=0;mt<2;mt++)
        Am[mt] = *(const s16x8*)&cct[mt*16+lo][kb];
      #pragma unroll
      for (int j=0;j<2;j++){
        int nt = w + j*NW;
        if (nt<13){
          s16x8 Bf = *(const s16x8*)(f1s + ((size_t)(nt*19+ks)*64 + lane)*8);
          #pragma unroll
          for (int mt=0;mt<2;mt++)
            acc2[mt][j] = __builtin_amdgcn_mfma_f32_16x16x32_bf16(Am[mt], Bf, acc2[mt][j], 0,0,0);
        }
      }
    }
  }
  {
    float f2c[2];
    #pragma unroll
    for (int j=0;j<2;j++){
      int nt = w + j*NW;
      int jj = nt*16+lo;
      f2c[j] = (nt<13 && jj<200)? F2[jj] : 0.f;
    }
    #pragma unroll
    for (int mt=0;mt<2;mt++)
      #pragma unroll
      for (int r=0;r<4;r++){
        float s = 0.f;
        #pragma unroll
        for (int j=0;j<2;j++){
          float v = acc2[mt][j][r];
          s += (v>0.f? v:0.f) * f2c[j];
        }
        s += __shfl_xor(s,1,64); s += __shfl_xor(s,2,64);
        s += __shfl_xor(s,4,64); s += __shfl_xor(s,8,64);
        if (lo==0) wdP[w][mt*16+qd*4+r] = s;
      }
  }
  __syncthreads();
  if (tid<TB*10){
    int n=tid, b=n/10, k=n%10;
    float v = 0.f;
    #pragma unroll
    for (int ww=0;ww<NW;ww++) v += wdP[ww][n];
    float ang = fabsf(xse[b][1][k]-AngleM[k]) * (1.0f/360.0f);
    v += xse[b][0][k]*F2[200] + ang*F2[201] + b2[0];
    wdL[n] = v>0.f? v : 0.f;
  }
  __syncthreads();
  if (tid<TB && b0+tid < 512){
    int b=tid;
    float m = wdL[b*10];
    #pragma unroll
    for (int k=1;k<10;k++) m = fmaxf(m, wdL[b*10+k]);
    float e[10]; float s=0.f;
    #pragma unroll
    for (int k=0;k<10;k++){ e[k]=__expf(wdL[b*10+k]-m); s+=e[k]; }
    float inv = rcpf(s);
    #pragma unroll
    for (int k=0;k<10;k++) smg[t*5120 + k*512 + b0+b] = e[k]*inv;
  }
}

// ====== final: gather scramble, fuse, preds (+ labels copy fused); TBF=4 ======
__global__ __launch_bounds__(NTHR,3) void kern_final(
    const float* __restrict__ li, const float* __restrict__ labels,
    const float* __restrict__ ff, const float* __restrict__ bff,
    const float* __restrict__ fuse1, const float* __restrict__ biasf,
    const float* __restrict__ Wout, const float* __restrict__ biasout,
    const float* __restrict__ a, const float* wsf,
    const unsigned* __restrict__ con1u, float* __restrict__ outp)
{
  __shared__ unsigned conTu[40][152];
  __shared__ float xs17[TBF][17][10];
  __shared__ float cats[TBF][300];
  __shared__ float wa3s[TBF][10];
  __shared__ float dss[TBF][17];
  __shared__ float wAs[10];
  __shared__ float fup1[8][64], fup2[8][64];
  const int tid=threadIdx.x, t=blockIdx.y, bt=blockIdx.x, b0=bt*TBF;
  if (tid>=NTHR-TBF && tid<NTHR){
    int b = tid-(NTHR-TBF);
    outp[16384 + t*512 + b0+b] = labels[(b0+b)*32+t];
  }
  for (int p=tid;p<TBF*170;p+=NTHR){
    int b=p/170, r=p%170, f=r/10, k=r%10;
    xs17[b][f][k] = li[(((b0+b)*32+t)*28 + 11+f)*10 + k];
  }
  if (tid<10) wAs[tid] = wsf[OFF_WA+tid];
  for (int p=tid;p<6000;p+=NTHR){   // direct-bg con1u layout
    int n4=p/150, op=p%150;
    int b=n4/10, k=n4%10, bg=b0+b;
    conTu[n4][op] = con1u[ ((size_t)(t*512+bg)*10 + k)*150 + op ];
  }
  __syncthreads();
  for (int p=tid;p<TBF*10;p+=NTHR){
    int b=p/10, k=p%10;
    int g = (b0+b)*10+k;
    wa3s[b][k] = wsf[OFF_SM + t*5120 + (g>>9)*512 + (g&511)];
  }
  for (int p=tid;p<TBF*17;p+=NTHR){
    int b=p/17, f=p%17; float s=0.f;
    #pragma unroll
    for (int k=0;k<10;k++) s += xs17[b][f][k]*wAs[k];
    dss[b][f]=s;
  }
  __syncthreads();
  const u16* conT = (const u16*)conTu;
  for (int p=tid;p<TBF*300;p+=NTHR){
    int b=p/300, h=p%300;
    float s=0.f;
    #pragma unroll
    for (int k=0;k<10;k++)
      s += bfu(conT[(b*10+k)*304 + h]) * wa3s[b][k];
    cats[b][h]=s;
  }
  __syncthreads();
  const int w = tid>>6, lane = tid&63;
  const int o1 = lane;
  const bool o2v = lane<36;
  const int o2 = o2v ? (64+lane) : 99;
  if (w<8){
    int b=w>>1, half=w&1;
    float fu1 = half? 0.f : biasf[o1];
    float fu2 = half? 0.f : biasf[o2];
    const int hb = half*150;
    for (int h=hb; h<hb+150; h++){
      float cv = cats[b][h];
      fu1 += cv*fuse1[h*100+o1];
      fu2 += cv*fuse1[h*100+o2];
    }
    fup1[w][lane]=fu1; fup2[w][lane]=fu2;
  }
  __syncthreads();
  if (w<TBF){
    const int b=w, bg=b0+b;
    const float aa = a[0], swa = wsf[OFF_SWA];
    float fu1 = fup1[2*b][lane] + fup1[2*b+1][lane];
    float fu2 = fup2[2*b][lane] + fup2[2*b+1][lane];
    float fd1 = bff[o1]*swa, fd2 = bff[o2]*swa;
    #pragma unroll
    for (int f=0;f<17;f++){
      float dv = dss[b][f];
      fd1 += ff[o1*17+f]*dv;
      fd2 += ff[o2*17+f]*dv;
    }
    float v = (aa*fu1+(1.f-aa)*fd1)*Wout[o1];
    if (o2v) v += (aa*fu2+(1.f-aa)*fd2)*Wout[o2];
    #pragma unroll
    for (int off=32;off>=1;off>>=1) v += __shfl_xor(v,off,64);
    if (lane==0) outp[t*512+bg] = v + biasout[0];
  }
}

// ================= weight prep =================
__global__ void kprep(const float* __restrict__ Wih, const float* __restrict__ b_ih,
                      const float* __restrict__ b_hh, const float* __restrict__ Wt,
                      const float* __restrict__ bt_ih, const float* __restrict__ bt_hh,
                      const float* __restrict__ wp, const float* __restrict__ F1,
                      const float* __restrict__ b1, float* __restrict__ wsf)
{
  int n = blockIdx.x*256 + threadIdx.x;
  if (n < 92416){   // wp A-frags
    int jp=n&3, lane=(n>>2)&63, rest=n>>8;
    int ks=rest%19, mt=rest/19;
    int m = mt*16 + (lane&15);
    int k = ks*32 + (lane>>4)*8 + 2*jp;
    float v0 = (m<300 && k  <600)? wp[m*600+k  ] : 0.f;
    float v1 = (m<300 && k+1<600)? wp[m*600+k+1] : 0.f;
    ((unsigned*)wsf)[OFF_WBF2+n] = ((unsigned)f2usr(v1)<<16) | f2usr(v0);
    return;
  }
  n -= 92416;
  if (n < 63232){   // F1 B-frags; row 600 = b1
    int jp=n&3, lane=(n>>2)&63, rest=n>>8;
    int ks=rest%19, nt=rest/19;
    int col = nt*16 + (lane&15);
    int k = ks*32 + (lane>>4)*8 + 2*jp;
    float v0=0.f, v1=0.f;
    if (col<200){
      v0 = (k  <600)? F1[k*200+col]     : (k  ==600? b1[col] : 0.f);
      v1 = (k+1<600)? F1[(k+1)*200+col] : (k+1==600? b1[col] : 0.f);
    }
    ((unsigned*)wsf)[OFF_F1S+n] = ((unsigned)f2usr(v1)<<16) | f2usr(v0);
    return;
  }
  n -= 63232;
  if (n < 72960){   // cells B-frags [k][ht][g][l32][4]: B[kk][h], kk==11 -> bias
    int jp=n&3, l32=(n>>2)&31, rest=n>>7;
    int g=rest%3, rest2=rest/3, ht=rest2%19, k=rest2/19;
    int lo=l32&15, q16=l32>>4;
    int h = ht*16 + lo;
    int kk0 = q16*8 + 2*jp;
    float v0=0.f, v1=0.f;
    if (h < 300){
      int G = h + (g==0?0:(g==1?600:900));
      v0 = (kk0  <11)? Wih[(k*1200+G)*11+kk0]
         : (kk0 ==11? b_ih[k*1200+G]+b_hh[k*1200+G] : 0.f);
      int kk1 = kk0+1;
      v1 = (kk1  <11)? Wih[(k*1200+G)*11+kk1]
         : (kk1 ==11? b_ih[k*1200+G]+b_hh[k*1200+G] : 0.f);
    }
    ((unsigned*)wsf)[OFF_WCELL+n] = ((unsigned)f2usr(v1)<<16) | f2usr(v0);
    return;
  }
  n -= 72960;
  if (n < 900){
    int h=n%300, g=n/300;
    int G = h + (g==0?0:(g==1?600:900));
    wsf[OFF_BTP+n] = bt_ih[G]+bt_hh[G]; return;
  }
  n -= 900;
  if (n < 3600){
    int h=n%300; int q=n/300; int g=q%3, e=q/3;
    int G = h + (g==0?0:(g==1?600:900));
    wsf[OFF_WTP+n] = Wt[G*4+e]; return;
  }
}

__global__ void kprep2(const float* __restrict__ DisM, float* __restrict__ wsf){
  if (threadIdx.x==0 && blockIdx.x==0){
    float m = DisM[0];
    for (int k=1;k<10;k++) m = fmaxf(m, DisM[k]);
    float e[10]; float s=0.f;
    for (int k=0;k<10;k++){ e[k]=__expf(DisM[k]-m); s+=e[k]; }
    float inv=1.0f/s; float sw=0.f;
    for (int k=0;k<10;k++){ float v=e[k]*inv; wsf[OFF_WA+k]=v; sw+=v; }
    wsf[OFF_SWA]=sw;
  }
}

extern "C" void kernel_launch(void* const* d_in, const int* in_sizes, int n_in,
                              void* d_out, int out_size, void* d_ws, size_t ws_size,
                              hipStream_t stream)
{
  const float* li     = (const float*)d_in[0];
  const float* labels = (const float*)d_in[1];
  const float* exs    = (const float*)d_in[2];
  const float* DisM   = (const float*)d_in[3];
  const float* AngleM = (const float*)d_in[4];
  const float* Wih    = (const float*)d_in[5];
  const float* b_ih   = (const float*)d_in[6];
  const float* b_hh   = (const float*)d_in[7];
  const float* Wt     = (const float*)d_in[8];
  const float* bt_ih  = (const float*)d_in[9];
  const float* bt_hh  = (const float*)d_in[10];
  const float* wp     = (const float*)d_in[11];
  const float* bp     = (const float*)d_in[12];
  const float* F1     = (const float*)d_in[13];
  const float* b1     = (const float*)d_in[14];
  const float* F2     = (const float*)d_in[15];
  const float* b2     = (const float*)d_in[16];
  const float* ff     = (const float*)d_in[17];
  const float* bff    = (const float*)d_in[18];
  const float* fuse1  = (const float*)d_in[19];
  const float* biasf  = (const float*)d_in[20];
  const float* Wout   = (const float*)d_in[21];
  const float* biasout= (const float*)d_in[22];
  const float* a      = (const float*)d_in[23];
  float* wsf = (float*)d_ws;
  float* outp = (float*)d_out;
  unsigned* con1u = (unsigned*)((char*)d_ws + CON1_BYTE);
  u16* cong = (u16*)((char*)d_ws + CONG_BYTE);

  if (ws_size < WS_NEED_BYTES) return;  // proven available (R12 split ran)

  kprep<<<dim3(911), dim3(256), 0, stream>>>(Wih,b_ih,b_hh,Wt,bt_ih,bt_hh,wp,F1,b1,wsf);
  kprep2<<<dim3(1), dim3(64), 0, stream>>>(DisM, wsf);
  kern_cells<<<dim3(10,256), dim3(256), 0, stream>>>(li, wsf, cong);
  kern_main_split<<<dim3(NBT,32), NTHR, 0, stream>>>(li, exs, AngleM, bp, F2, b2,
                                                     wsf, con1u, wsf + OFF_SM, cong);
  kern_final<<<dim3(128,32), NTHR, 0, stream>>>(li, labels, ff, bff, fuse1, biasf,
                                                Wout, biasout, a, wsf, con1u, outp);
}

// Round 17
// 493.123 us; speedup vs baseline: 1.6478x; 1.0741x over previous
//
#include <hip/hip_runtime.h>
#include <hip/hip_bf16.h>

// GCLSTM: B=512, T=32, H=300, K=10. f32 in/out.
// R17 = R16 + (1) kern_final fuse1 GEMM on MFMA: D[b4][o112]=cats@fuse1,
// 7 Ntiles x 10 Ksteps, A from LDS cats (bf16 on the fly, rows>=4 zero),
// B pre-swizzled in ws (F1F table); epilogue on qd==0 lanes + 16-lane shfl
// reduce. (2) P1/P5/conTu copies as uint2 (rows 8B-aligned). Cells / wp /
// F1 phases byte-frozen from R16. ws need 198,267,520 <= proven 198,336,000.

#define TB 3
#define NBT 171           // ceil(512/3) blocks in b
#define NR 32             // cct rows (MFMA N)
#define NTHR 640          // 10 waves
#define NW 10
#define KP 616
#define TBF 4             // kern_final b-tile

// ws layout (u32 slots)
#define OFF_SM    0         // softmax [32][10][512] f32          163840
#define OFF_WBF2  163840    // wp A-frags [mt19][ks19][lane64][4]  92416
#define OFF_F1S   256256    // F1 B-frags [nt13][ks19][lane64][4]  63232
#define OFF_WCELL 319488    // cells B-frags [k10][ht19][g3][l32][4] 72960
#define OFF_BTP   392448    // g*300+h f32                           900
#define OFF_WTP   393348    // (e*3+g)*300+h f32                    3600
#define OFF_F1F   396948    // fuse1 B-frags [nt7][ks10][lane64][4] 17920
#define OFF_WA    414868    // softmax(DisM) f32                      10
#define OFF_SWA   414878    // sum(wA) f32                             1
#define BASE_U32  414880
#define CON1_BYTE ((size_t)BASE_U32 * 4)                  // 1,659,520
#define CONG_BYTE (CON1_BYTE + (size_t)98304000)          // 99,963,520
#define WS_NEED_BYTES (CONG_BYTE + (size_t)98304000)      // 198,267,520 (< proven 198,336,000)

typedef __attribute__((ext_vector_type(8))) short s16x8;
typedef __attribute__((ext_vector_type(4))) float f32x4;
typedef unsigned short u16;

__device__ __forceinline__ float rcpf(float x){ return __builtin_amdgcn_rcpf(x); }
__device__ __forceinline__ float sigf(float x){ return rcpf(1.0f+__expf(-x)); }
__device__ __forceinline__ float tanhf_(float x){ return 1.0f - 2.0f*rcpf(__expf(2.0f*x)+1.0f); }
__device__ __forceinline__ float bfu(u16 u){ return __uint_as_float(((unsigned)u)<<16); }
__device__ __forceinline__ u16 f2us(float f){ return (u16)(__float_as_uint(f)>>16); }
__device__ __forceinline__ u16 f2usr(float f){   // RNE bf16
  __hip_bfloat16 h = __float2bfloat16(f);
  return *(u16*)&h;
}

// ===== cells-MFMA (frozen from R16) =====
__global__ __launch_bounds__(256,4) void kern_cells(
    const float* __restrict__ li, const float* wsf, u16* __restrict__ cong)
{
  __shared__ __align__(16) float xs[64][12];
  const int tid=threadIdx.x, k=blockIdx.x;
  const int tbase = blockIdx.y*64;
  const int t = tbase>>9, bg0 = tbase&511;
  for (int p=tid; p<64*11; p+=256){
    int r=p/11, i=p%11;
    xs[r][i] = li[(((size_t)(bg0+r)*32+t)*28+i)*10+k];
  }
  if (tid<64) xs[tid][11] = 1.0f;
  __syncthreads();
  const int w = tid>>6, lane = tid&63, lo=lane&15, qd=lane>>4;
  short av[8];
  #pragma unroll
  for (int j=0;j<8;j++){
    int kk = qd*8+j;
    float v = (kk<12)? xs[w*16+lo][kk] : 0.f;
    av[j] = (short)f2usr(v);
  }
  s16x8 Ax = (s16x8){av[0],av[1],av[2],av[3],av[4],av[5],av[6],av[7]};
  const unsigned* wc = (const unsigned*)wsf + OFF_WCELL;
  const s16x8 Z = (s16x8){0,0,0,0,0,0,0,0};
  for (int ht=0; ht<19; ht++){
    s16x8 Bi=Z, Bg=Z, Bo=Z;
    if (qd<2){
      const unsigned* bb = wc + (((k*19+ht)*3)*32 + qd*16+lo)*4;
      Bi = *(const s16x8*)(bb);
      Bg = *(const s16x8*)(bb + 32*4);
      Bo = *(const s16x8*)(bb + 64*4);
    }
    f32x4 gi={0.f,0.f,0.f,0.f}, gg={0.f,0.f,0.f,0.f}, go={0.f,0.f,0.f,0.f};
    gi = __builtin_amdgcn_mfma_f32_16x16x32_bf16(Ax, Bi, gi, 0,0,0);
    gg = __builtin_amdgcn_mfma_f32_16x16x32_bf16(Ax, Bg, gg, 0,0,0);
    go = __builtin_amdgcn_mfma_f32_16x16x32_bf16(Ax, Bo, go, 0,0,0);
    int h = ht*16+lo;
    if (h<300){
      #pragma unroll
      for (int r=0;r<4;r++){
        float hv = sigf(go[r]) * tanhf_( sigf(gi[r]) * tanhf_(gg[r]) );
        int tb = tbase + w*16 + qd*4 + r;
        cong[((size_t)tb*10+k)*300 + h] = f2usr(hv);
      }
    }
  }
}

// ============ kern_main_split (P1/P5 now uint2; else frozen) ============
__global__ __launch_bounds__(NTHR,2) void kern_main_split(
    const float* __restrict__ li, const float* __restrict__ exs,
    const float* __restrict__ AngleM, const float* __restrict__ bp,
    const float* __restrict__ F2, const float* __restrict__ b2,
    const float* wsf, unsigned* __restrict__ con1u, float* smg,
    const u16* __restrict__ cong)
{
  __shared__ __align__(16) u16 cct[NR][KP];   // 39,424 B
  __shared__ float xse[TB][2][10];
  __shared__ float exss[TB][4];
  __shared__ float wdP[NW][NR];
  __shared__ float wdL[NR];
  const int tid = threadIdx.x;
  const int t = blockIdx.y, bt = blockIdx.x, b0 = bt*TB;
  const int w = tid>>6, lane = tid&63, lo = lane&15, qd = lane>>4;

  for (int p=tid;p<TB*20;p+=NTHR){
    int b=p/20, r=p%20, rr=r/10, k=r%10;
    int bg = b0+b; if (bg>511) bg=511;
    xse[b][rr][k] = li[((bg*32+t)*28 + (rr?10:8))*10 + k];
  }
  for (int p=tid;p<TB*4;p+=NTHR){
    int b=p/4, e=p%4;
    int bg = b0+b; if (bg>511) bg=511;
    exss[b][e] = exs[(bg*32+t)*4+e];
  }
  for (int p=tid; p<30*4; p+=NTHR){
    int n=p/4, c=p%4;
    ((unsigned*)&cct[n][600])[c] = 0u;
  }
  __syncthreads();

  // ---- P1: uint2 copies; con(t) -> cols 0-299, con(t-1) -> cols 300-599 ----
  const int nh = (t==0)?1:2;
  for (int p=tid; p<nh*TB*750; p+=NTHR){
    int half=p/(TB*750), r=p%(TB*750), n=r/75, op=r%75;
    int tp = half? t-1 : t;
    int bg = b0 + n/10; if (bg>511) bg=511;
    uint2 v = *(const uint2*)((const unsigned*)cong +
                ((size_t)(tp*512+bg)*10 + n%10)*150 + 2*op);
    *(uint2*)((unsigned*)&cct[n][300*half] + 2*op) = v;
  }
  __syncthreads();

  // ---- P2: wp-MFMA ----
  f32x4 acc[2][2];
  #pragma unroll
  for (int i=0;i<2;i++)
    #pragma unroll
    for (int nt=0;nt<2;nt++) acc[i][nt] = (f32x4){0.f,0.f,0.f,0.f};
  if (t>0){
    const u16* wbfA = (const u16*)((const unsigned*)wsf + OFF_WBF2);
    for (int ks=0; ks<19; ks++){
      const int kb = ks*32 + qd*8;
      s16x8 Bv[2];
      #pragma unroll
      for (int nt=0;nt<2;nt++)
        Bv[nt] = *(const s16x8*)&cct[nt*16+lo][kb];
      #pragma unroll
      for (int i=0;i<2;i++){
        int mt = w*2+i;
        if (mt<19){
          s16x8 Av = *(const s16x8*)(wbfA + ((size_t)(mt*19+ks)*64 + lane)*8);
          #pragma unroll
          for (int nt=0;nt<2;nt++)
            acc[i][nt] = __builtin_amdgcn_mfma_f32_16x16x32_bf16(Av, Bv[nt], acc[i][nt], 0,0,0);
        }
      }
    }
  }
  __syncthreads();

  if (t>0){
    #pragma unroll
    for (int i=0;i<2;i++){
      int mt = w*2+i;
      if (mt<19 && (mt<18 || qd<3)){
        int ob = mt*16 + qd*4;
        float p0=bp[ob], p1=bp[ob+1], p2=bp[ob+2], p3=bp[ob+3];
        #pragma unroll
        for (int nt=0;nt<2;nt++){
          int n = nt*16+lo;
          float v0=acc[i][nt][0]+p0, v1=acc[i][nt][1]+p1,
                v2=acc[i][nt][2]+p2, v3=acc[i][nt][3]+p3;
          unsigned w0 = ((unsigned)f2us(v1>0.f?v1:0.f)<<16) | f2us(v0>0.f?v0:0.f);
          unsigned w1 = ((unsigned)f2us(v3>0.f?v3:0.f)<<16) | f2us(v2>0.f?v2:0.f);
          *(unsigned*)&cct[n][ob]   = w0;
          *(unsigned*)&cct[n][ob+2] = w1;
        }
      }
    }
  }
  // ---- P3: htarget ----
  for (int p=tid; p<TB*300; p+=NTHR){
    int b=p/300, o=p%300;
    float ai=0.f, ag=0.f, ao=0.f;
    #pragma unroll
    for (int e=0;e<4;e++){
      float xv = exss[b][e];
      ai += wsf[OFF_WTP+(e*3+0)*300+o]*xv;
      ag += wsf[OFF_WTP+(e*3+1)*300+o]*xv;
      ao += wsf[OFF_WTP+(e*3+2)*300+o]*xv;
    }
    ai += wsf[OFF_BTP+o]; ag += wsf[OFF_BTP+300+o]; ao += wsf[OFF_BTP+600+o];
    u16 u = f2usr( sigf(ao)*tanhf_(sigf(ai)*tanhf_(ag)) );
    #pragma unroll
    for (int k=0;k<10;k++) cct[b*10+k][300+o] = u;
  }
  for (int p=tid; p<30*4; p+=NTHR){
    int n=p/4, c=p%4;
    ((unsigned*)&cct[n][600])[c] = (c==0)? 0x00003f80u : 0u;
  }
  __syncthreads();

  // ---- P5: uint2 stores of con1 tile ----
  for (int p=tid; p<TB*750; p+=NTHR){
    int n=p/75, op=p%75;
    int bg = b0 + n/10;
    if (bg < 512){
      uint2 v = *(const uint2*)((unsigned*)&cct[n][0] + 2*op);
      *(uint2*)(con1u + ((size_t)(t*512+bg)*10 + n%10)*150 + 2*op) = v;
    }
  }

  // ---- P4: F1-MFMA ----
  f32x4 acc2[2][2];
  #pragma unroll
  for (int mt=0;mt<2;mt++)
    #pragma unroll
    for (int j=0;j<2;j++) acc2[mt][j] = (f32x4){0.f,0.f,0.f,0.f};
  {
    const u16* f1s = (const u16*)((const unsigned*)wsf + OFF_F1S);
    for (int ks=0; ks<19; ks++){
      const int kb = ks*32 + qd*8;
      s16x8 Am[2];
      #pragma unroll
      for (int mt=0;mt<2;mt++)
        Am[mt] = *(const s16x8*)&cct[mt*16+lo][kb];
      #pragma unroll
      for (int j=0;j<2;j++){
        int nt = w + j*NW;
        if (nt<13){
          s16x8 Bf = *(const s16x8*)(f1s + ((size_t)(nt*19+ks)*64 + lane)*8);
          #pragma unroll
          for (int mt=0;mt<2;mt++)
            acc2[mt][j] = __builtin_amdgcn_mfma_f32_16x16x32_bf16(Am[mt], Bf, acc2[mt][j], 0,0,0);
        }
      }
    }
  }
  {
    float f2c[2];
    #pragma unroll
    for (int j=0;j<2;j++){
      int nt = w + j*NW;
      int jj = nt*16+lo;
      f2c[j] = (nt<13 && jj<200)? F2[jj] : 0.f;
    }
    #pragma unroll
    for (int mt=0;mt<2;mt++)
      #pragma unroll
      for (int r=0;r<4;r++){
        float s = 0.f;
        #pragma unroll
        for (int j=0;j<2;j++){
          float v = acc2[mt][j][r];
          s += (v>0.f? v:0.f) * f2c[j];
        }
        s += __shfl_xor(s,1,64); s += __shfl_xor(s,2,64);
        s += __shfl_xor(s,4,64); s += __shfl_xor(s,8,64);
        if (lo==0) wdP[w][mt*16+qd*4+r] = s;
      }
  }
  __syncthreads();
  if (tid<TB*10){
    int n=tid, b=n/10, k=n%10;
    float v = 0.f;
    #pragma unroll
    for (int ww=0;ww<NW;ww++) v += wdP[ww][n];
    float ang = fabsf(xse[b][1][k]-AngleM[k]) * (1.0f/360.0f);
    v += xse[b][0][k]*F2[200] + ang*F2[201] + b2[0];
    wdL[n] = v>0.f? v : 0.f;
  }
  __syncthreads();
  if (tid<TB && b0+tid < 512){
    int b=tid;
    float m = wdL[b*10];
    #pragma unroll
    for (int k=1;k<10;k++) m = fmaxf(m, wdL[b*10+k]);
    float e[10]; float s=0.f;
    #pragma unroll
    for (int k=0;k<10;k++){ e[k]=__expf(wdL[b*10+k]-m); s+=e[k]; }
    float inv = rcpf(s);
    #pragma unroll
    for (int k=0;k<10;k++) smg[t*5120 + k*512 + b0+b] = e[k]*inv;
  }
}

// ====== final: gather scramble, cats, fuse via MFMA, preds ======
__global__ __launch_bounds__(NTHR,3) void kern_final(
    const float* __restrict__ li, const float* __restrict__ labels,
    const float* __restrict__ ff, const float* __restrict__ bff,
    const float* __restrict__ biasf, const float* __restrict__ Wout,
    const float* __restrict__ biasout, const float* __restrict__ a,
    const float* wsf, const unsigned* __restrict__ con1u,
    float* __restrict__ outp)
{
  __shared__ unsigned conTu[40][152];   // [n][o-pairs]; u16 view stride 304
  __shared__ float xs17[TBF][17][10];
  __shared__ __align__(16) float cats[TBF][320];   // cols 300-319 zero pad
  __shared__ float wa3s[TBF][10];
  __shared__ float dss[TBF][17];
  __shared__ float wAs[10];
  __shared__ float part[7][TBF];
  const int tid=threadIdx.x, t=blockIdx.y, bt=blockIdx.x, b0=bt*TBF;
  const int w = tid>>6, lane = tid&63, lo = lane&15, qd = lane>>4;
  if (tid>=NTHR-TBF && tid<NTHR){   // fused labels_r copy
    int b = tid-(NTHR-TBF);
    outp[16384 + t*512 + b0+b] = labels[(b0+b)*32+t];
  }
  for (int p=tid;p<TBF*170;p+=NTHR){
    int b=p/170, r=p%170, f=r/10, k=r%10;
    xs17[b][f][k] = li[(((b0+b)*32+t)*28 + 11+f)*10 + k];
  }
  if (tid<10) wAs[tid] = wsf[OFF_WA+tid];
  for (int p=tid;p<3000;p+=NTHR){   // uint2 conTu load
    int n4=p/75, op=p%75;
    int b=n4/10, k=n4%10, bg=b0+b;
    uint2 v = *(const uint2*)(con1u + ((size_t)(t*512+bg)*10 + k)*150 + 2*op);
    *(uint2*)(&conTu[n4][2*op]) = v;
  }
  __syncthreads();
  for (int p=tid;p<TBF*10;p+=NTHR){
    int b=p/10, k=p%10;
    int g = (b0+b)*10+k;   // flat-reshape scramble
    wa3s[b][k] = wsf[OFF_SM + t*5120 + (g>>9)*512 + (g&511)];
  }
  for (int p=tid;p<TBF*17;p+=NTHR){
    int b=p/17, f=p%17; float s=0.f;
    #pragma unroll
    for (int k=0;k<10;k++) s += xs17[b][f][k]*wAs[k];
    dss[b][f]=s;
  }
  __syncthreads();
  const u16* conT = (const u16*)conTu;
  for (int p=tid;p<TBF*300;p+=NTHR){
    int b=p/300, h=p%300;
    float s=0.f;
    #pragma unroll
    for (int k=0;k<10;k++)
      s += bfu(conT[(b*10+k)*304 + h]) * wa3s[b][k];
    cats[b][h]=s;
  }
  for (int p=tid;p<TBF*20;p+=NTHR){
    int b=p/20, c=p%20;
    cats[b][300+c] = 0.f;
  }
  __syncthreads();
  // ---- fuse1 MFMA: D[b 4][o 112] = cats[4x320] @ fuse1[320x112]; wave=Ntile ----
  if (w < 7){
    f32x4 D = (f32x4){0.f,0.f,0.f,0.f};
    const u16* f1f = (const u16*)((const unsigned*)wsf + OFF_F1F);
    for (int ks=0; ks<10; ks++){
      const int kb = ks*32 + qd*8;
      short av[8];
      #pragma unroll
      for (int j=0;j<8;j++){
        float v = (lo<4)? cats[lo][kb+j] : 0.f;
        av[j] = (short)f2usr(v);
      }
      s16x8 Ax = (s16x8){av[0],av[1],av[2],av[3],av[4],av[5],av[6],av[7]};
      s16x8 Bf = *(const s16x8*)(f1f + ((size_t)(w*10+ks)*64 + lane)*8);
      D = __builtin_amdgcn_mfma_f32_16x16x32_bf16(Ax, Bf, D, 0,0,0);
    }
    if (qd==0){   // D rows 0..3 = b; col = w*16+lo
      int o = w*16+lo;
      bool ov = o<100;
      float aa = a[0], swa = wsf[OFF_SWA];
      float bfo = ov? biasf[o] : 0.f;
      float bffo = ov? bff[o]*swa : 0.f;
      float wo = ov? Wout[o] : 0.f;
      #pragma unroll
      for (int r=0;r<4;r++){
        float fu = D[r] + bfo;
        float fd = bffo;
        if (ov){
          #pragma unroll
          for (int f=0;f<17;f++) fd += ff[o*17+f]*dss[r][f];
        }
        float v = (aa*fu + (1.f-aa)*fd) * wo;
        v += __shfl_xor(v,1,64); v += __shfl_xor(v,2,64);
        v += __shfl_xor(v,4,64); v += __shfl_xor(v,8,64);
        if (lo==0) part[w][r] = v;
      }
    }
  }
  __syncthreads();
  if (tid<TBF){
    int b=tid;
    float v = biasout[0];
    #pragma unroll
    for (int ww=0;ww<7;ww++) v += part[ww][b];
    outp[t*512 + b0+b] = v;
  }
}

// ================= weight prep =================
__global__ void kprep(const float* __restrict__ Wih, const float* __restrict__ b_ih,
                      const float* __restrict__ b_hh, const float* __restrict__ Wt,
                      const float* __restrict__ bt_ih, const float* __restrict__ bt_hh,
                      const float* __restrict__ wp, const float* __restrict__ F1,
                      const float* __restrict__ b1, const float* __restrict__ fuse1,
                      float* __restrict__ wsf)
{
  int n = blockIdx.x*256 + threadIdx.x;
  if (n < 92416){   // wp A-frags
    int jp=n&3, lane=(n>>2)&63, rest=n>>8;
    int ks=rest%19, mt=rest/19;
    int m = mt*16 + (lane&15);
    int k = ks*32 + (lane>>4)*8 + 2*jp;
    float v0 = (m<300 && k  <600)? wp[m*600+k  ] : 0.f;
    float v1 = (m<300 && k+1<600)? wp[m*600+k+1] : 0.f;
    ((unsigned*)wsf)[OFF_WBF2+n] = ((unsigned)f2usr(v1)<<16) | f2usr(v0);
    return;
  }
  n -= 92416;
  if (n < 63232){   // F1 B-frags; row 600 = b1
    int jp=n&3, lane=(n>>2)&63, rest=n>>8;
    int ks=rest%19, nt=rest/19;
    int col = nt*16 + (lane&15);
    int k = ks*32 + (lane>>4)*8 + 2*jp;
    float v0=0.f, v1=0.f;
    if (col<200){
      v0 = (k  <600)? F1[k*200+col]     : (k  ==600? b1[col] : 0.f);
      v1 = (k+1<600)? F1[(k+1)*200+col] : (k+1==600? b1[col] : 0.f);
    }
    ((unsigned*)wsf)[OFF_F1S+n] = ((unsigned)f2usr(v1)<<16) | f2usr(v0);
    return;
  }
  n -= 63232;
  if (n < 72960){   // cells B-frags
    int jp=n&3, l32=(n>>2)&31, rest=n>>7;
    int g=rest%3, rest2=rest/3, ht=rest2%19, k=rest2/19;
    int lo=l32&15, q16=l32>>4;
    int h = ht*16 + lo;
    int kk0 = q16*8 + 2*jp;
    float v0=0.f, v1=0.f;
    if (h < 300){
      int G = h + (g==0?0:(g==1?600:900));
      v0 = (kk0  <11)? Wih[(k*1200+G)*11+kk0]
         : (kk0 ==11? b_ih[k*1200+G]+b_hh[k*1200+G] : 0.f);
      int kk1 = kk0+1;
      v1 = (kk1  <11)? Wih[(k*1200+G)*11+kk1]
         : (kk1 ==11? b_ih[k*1200+G]+b_hh[k*1200+G] : 0.f);
    }
    ((unsigned*)wsf)[OFF_WCELL+n] = ((unsigned)f2usr(v1)<<16) | f2usr(v0);
    return;
  }
  n -= 72960;
  if (n < 900){
    int h=n%300, g=n/300;
    int G = h + (g==0?0:(g==1?600:900));
    wsf[OFF_BTP+n] = bt_ih[G]+bt_hh[G]; return;
  }
  n -= 900;
  if (n < 3600){
    int h=n%300; int q=n/300; int g=q%3, e=q/3;
    int G = h + (g==0?0:(g==1?600:900));
    wsf[OFF_WTP+n] = Wt[G*4+e]; return;
  }
  n -= 3600;
  if (n < 17920){   // fuse1 B-frags [nt7][ks10][lane][4]: B[kk][o], kk<300, o<100
    int jp=n&3, lane=(n>>2)&63, rest=n>>8;
    int ks=rest%10, nt=rest/10;
    int col = nt*16 + (lane&15);
    int kk0 = ks*32 + (lane>>4)*8 + 2*jp;
    float v0 = (col<100 && kk0  <300)? fuse1[kk0*100+col]     : 0.f;
    float v1 = (col<100 && kk0+1<300)? fuse1[(kk0+1)*100+col] : 0.f;
    ((unsigned*)wsf)[OFF_F1F+n] = ((unsigned)f2usr(v1)<<16) | f2usr(v0);
    return;
  }
}

__global__ void kprep2(const float* __restrict__ DisM, float* __restrict__ wsf){
  if (threadIdx.x==0 && blockIdx.x==0){
    float m = DisM[0];
    for (int k=1;k<10;k++) m = fmaxf(m, DisM[k]);
    float e[10]; float s=0.f;
    for (int k=0;k<10;k++){ e[k]=__expf(DisM[k]-m); s+=e[k]; }
    float inv=1.0f/s; float sw=0.f;
    for (int k=0;k<10;k++){ float v=e[k]*inv; wsf[OFF_WA+k]=v; sw+=v; }
    wsf[OFF_SWA]=sw;
  }
}

extern "C" void kernel_launch(void* const* d_in, const int* in_sizes, int n_in,
                              void* d_out, int out_size, void* d_ws, size_t ws_size,
                              hipStream_t stream)
{
  const float* li     = (const float*)d_in[0];
  const float* labels = (const float*)d_in[1];
  const float* exs    = (const float*)d_in[2];
  const float* DisM   = (const float*)d_in[3];
  const float* AngleM = (const float*)d_in[4];
  const float* Wih    = (const float*)d_in[5];
  const float* b_ih   = (const float*)d_in[6];
  const float* b_hh   = (const float*)d_in[7];
  const float* Wt     = (const float*)d_in[8];
  const float* bt_ih  = (const float*)d_in[9];
  const float* bt_hh  = (const float*)d_in[10];
  const float* wp     = (const float*)d_in[11];
  const float* bp     = (const float*)d_in[12];
  const float* F1     = (const float*)d_in[13];
  const float* b1     = (const float*)d_in[14];
  const float* F2     = (const float*)d_in[15];
  const float* b2     = (const float*)d_in[16];
  const float* ff     = (const float*)d_in[17];
  const float* bff    = (const float*)d_in[18];
  const float* fuse1  = (const float*)d_in[19];
  const float* biasf  = (const float*)d_in[20];
  const float* Wout   = (const float*)d_in[21];
  const float* biasout= (const float*)d_in[22];
  const float* a      = (const float*)d_in[23];
  float* wsf = (float*)d_ws;
  float* outp = (float*)d_out;
  unsigned* con1u = (unsigned*)((char*)d_ws + CON1_BYTE);
  u16* cong = (u16*)((char*)d_ws + CONG_BYTE);

  if (ws_size < WS_NEED_BYTES) return;  // proven available (R12 split ran)

  kprep<<<dim3(981), dim3(256), 0, stream>>>(Wih,b_ih,b_hh,Wt,bt_ih,bt_hh,wp,F1,b1,fuse1,wsf);
  kprep2<<<dim3(1), dim3(64), 0, stream>>>(DisM, wsf);
  kern_cells<<<dim3(10,256), dim3(256), 0, stream>>>(li, wsf, cong);
  kern_main_split<<<dim3(NBT,32), NTHR, 0, stream>>>(li, exs, AngleM, bp, F2, b2,
                                                     wsf, con1u, wsf + OFF_SM, cong);
  kern_final<<<dim3(128,32), NTHR, 0, stream>>>(li, labels, ff, bff, biasf,
                                                Wout, biasout, a, wsf, con1u, outp);
}